// Round 8
// baseline (4182.487 us; speedup 1.0000x reference)
//
#include <hip/hip_runtime.h>
#include <stdint.h>

// Codec forward. Round 6: E1 ported to the 256^2 8-phase MFMA schedule
// (T2 swizzle + T3/T4 counted-vmcnt + T5 setprio), expressed as ONE plain
// bf16 GEMM with K'=9216 via 3 segment pointers:
//   seg0: xhi @ w1ehi, seg1: xlo @ w1ehi, seg2: xhi @ w1elo.
// E2/D1/D2 stay on the verified Round-4 2-phase MFMA path.
// Round 7: resubmit unchanged (container infra failure, no signal).

#define IMG_DIM 3072
#define HID     16384
#define NCODE   256
#define DCODE   64

typedef short bf16x8 __attribute__((ext_vector_type(8)));
typedef float f32x4 __attribute__((ext_vector_type(4)));

__device__ __forceinline__ uint16_t bf16rne(float f) {
    uint32_t u = __float_as_uint(f);
    return (uint16_t)((u + 0x7fffu + ((u >> 16) & 1u)) >> 16);
}
__device__ __forceinline__ float b2f(uint16_t h) {
    return __uint_as_float((uint32_t)h << 16);
}

#define GLLDS(g, l)                                                        \
    __builtin_amdgcn_global_load_lds(                                      \
        (const __attribute__((address_space(1))) uint32_t*)(const void*)(g), \
        (__attribute__((address_space(3))) uint32_t*)(void*)(l), 16, 0, 0)

// ---------------- Threefry2x32 (matches jax/_src/prng.py) ----------------
__host__ __device__ __forceinline__ uint32_t rotl32(uint32_t v, int d) {
    return (v << d) | (v >> (32 - d));
}

__host__ __device__ __forceinline__ void tf2x32(uint32_t k0, uint32_t k1,
                                                uint32_t& x0, uint32_t& x1) {
    uint32_t k2 = k0 ^ k1 ^ 0x1BD11BDAu;
    x0 += k0; x1 += k1;
    x0 += x1; x1 = rotl32(x1, 13); x1 ^= x0;
    x0 += x1; x1 = rotl32(x1, 15); x1 ^= x0;
    x0 += x1; x1 = rotl32(x1, 26); x1 ^= x0;
    x0 += x1; x1 = rotl32(x1,  6); x1 ^= x0;
    x0 += k1; x1 += k2 + 1u;
    x0 += x1; x1 = rotl32(x1, 17); x1 ^= x0;
    x0 += x1; x1 = rotl32(x1, 29); x1 ^= x0;
    x0 += x1; x1 = rotl32(x1, 16); x1 ^= x0;
    x0 += x1; x1 = rotl32(x1, 24); x1 ^= x0;
    x0 += k2; x1 += k0 + 2u;
    x0 += x1; x1 = rotl32(x1, 13); x1 ^= x0;
    x0 += x1; x1 = rotl32(x1, 15); x1 ^= x0;
    x0 += x1; x1 = rotl32(x1, 26); x1 ^= x0;
    x0 += x1; x1 = rotl32(x1,  6); x1 ^= x0;
    x0 += k0; x1 += k1 + 3u;
    x0 += x1; x1 = rotl32(x1, 17); x1 ^= x0;
    x0 += x1; x1 = rotl32(x1, 29); x1 ^= x0;
    x0 += x1; x1 = rotl32(x1, 16); x1 ^= x0;
    x0 += x1; x1 = rotl32(x1, 24); x1 ^= x0;
    x0 += k1; x1 += k2 + 4u;
    x0 += x1; x1 = rotl32(x1, 13); x1 ^= x0;
    x0 += x1; x1 = rotl32(x1, 15); x1 ^= x0;
    x0 += x1; x1 = rotl32(x1, 26); x1 ^= x0;
    x0 += x1; x1 = rotl32(x1,  6); x1 ^= x0;
    x0 += k2; x1 += k0 + 5u;
}

// ---------------- 8-phase 256^2 MFMA GEMM (C = act(A @ B^T + bias)) -------
// A,B: bf16 [rows][Kseg] per segment; K' = NSEG*Kseg (TPS K-tiles per seg).
// 512 threads = 8 waves (2M x 4N); per-wave C = 128x64; BK=64.
// LDS 128KB: [mat A/B][dbuf][khalf][256 rows][32 k bf16], rows 64B,
// st-swizzle: byte ^= ((r>>1)&1)<<5 | ((r>>2)&1)<<4 (both sides).
// EPI: 0 = f32; 1 = f32 tanh; 2 = bf16 tanh; 3 = bf16 hi/lo tanh.
template <int EPI, int TPS, int NSEG>
__global__ __launch_bounds__(512) void gemm8p(
    const uint16_t* __restrict__ a0, const uint16_t* __restrict__ a1,
    const uint16_t* __restrict__ a2,
    const uint16_t* __restrict__ b0, const uint16_t* __restrict__ b1,
    const uint16_t* __restrict__ b2,
    const float* __restrict__ biasp,
    float* __restrict__ Cf, uint16_t* __restrict__ Cb,
    uint16_t* __restrict__ Chi, uint16_t* __restrict__ Clo,
    int N, int Kseg) {
    __shared__ __align__(16) uint8_t lds[131072];
    constexpr int NT = TPS * NSEG;

    const int tid = threadIdx.x;
    const int lane = tid & 63, wv = tid >> 6;
    const int wm = wv >> 2, wn = wv & 3;
    const int la = lane & 15;
    const int lkb = (lane >> 4) << 4;  // k byte offset within 64B row

    // XCD-aware bijective swizzle (valid when nwg % 8 == 0)
    const int nbx = gridDim.x;
    const int nwg = nbx * gridDim.y;
    int flat = blockIdx.y * nbx + blockIdx.x;
    if ((nwg & 7) == 0) flat = (flat & 7) * (nwg >> 3) + (flat >> 3);
    const size_t bm = (size_t)(flat / nbx) * 256;
    const size_t bn = (size_t)(flat % nbx) * 256;

    auto swz = [](int r) -> int {
        return (((r >> 1) & 1) << 5) | (((r >> 2) & 1) << 4);
    };

    // stage one 16KB unit (mat, khalf) of tile tt into buf tt&1
    auto stage = [&](int tt, int mat, int kh) {
        if (tt >= NT) return;
        const int s = tt / TPS;            // TPS is constexpr
        const int tloc = tt - s * TPS;
        const uint16_t* mb;
        size_t rb;
        if (mat == 0) { mb = (s == 0 ? a0 : (s == 1 ? a1 : a2)); rb = bm; }
        else          { mb = (s == 0 ? b0 : (s == 1 ? b1 : b2)); rb = bn; }
        const int ub = mat * 65536 + (tt & 1) * 32768 + kh * 16384;
#pragma unroll
        for (int p = 0; p < 2; ++p) {
            const int off = (p * 512 + tid) * 16;    // phys byte in unit
            const int r = off >> 6;
            const int logc = (off & 63) ^ swz(r);    // inverse-swizzled source
            const uint16_t* src =
                mb + (rb + r) * (size_t)Kseg + tloc * 64 + kh * 32 + (logc >> 1);
            GLLDS(src, lds + ub + p * 8192 + wv * 1024);
        }
    };

    auto rdA = [&](int buf, int ks, int i) -> bf16x8 {
        const int r = wm * 128 + i * 16 + la;
        return *(const bf16x8*)(lds + buf * 32768 + ks * 16384 + r * 64 +
                                (lkb ^ swz(r)));
    };
    auto rdB = [&](int buf, int ks, int j) -> bf16x8 {
        const int r = wn * 64 + j * 16 + la;
        return *(const bf16x8*)(lds + 65536 + buf * 32768 + ks * 16384 + r * 64 +
                                (lkb ^ swz(r)));
    };

    f32x4 acc[8][4];
#pragma unroll
    for (int i = 0; i < 8; ++i)
#pragma unroll
        for (int j = 0; j < 4; ++j) acc[i][j] = (f32x4){0.f, 0.f, 0.f, 0.f};

    // prologue: t0 all 4 units, then t1 k0 units; keep newest 4 loads in flight
    stage(0, 0, 0); stage(0, 1, 0); stage(0, 0, 1); stage(0, 1, 1);
    stage(1, 0, 0); stage(1, 1, 0);
    __builtin_amdgcn_sched_barrier(0);
    if (NT > 1) asm volatile("s_waitcnt vmcnt(4)" ::: "memory");
    else        asm volatile("s_waitcnt vmcnt(0)" ::: "memory");
    __builtin_amdgcn_sched_barrier(0);
    __builtin_amdgcn_s_barrier();
    __builtin_amdgcn_sched_barrier(0);

    for (int tt = 0; tt < NT; ++tt) {
        const int buf = tt & 1;
        bf16x8 b[4];
#pragma unroll
        for (int ph = 0; ph < 4; ++ph) {
            const int ks = ph >> 1, ih = ph & 1;
            bf16x8 a[4];
#pragma unroll
            for (int ii = 0; ii < 4; ++ii) a[ii] = rdA(buf, ks, ih * 4 + ii);
            if (ih == 0) {
#pragma unroll
                for (int j = 0; j < 4; ++j) b[j] = rdB(buf, ks, j);
            }
            // prefetch: ph0: A-k1(t+1), ph1: B-k1(t+1), ph2: A-k0(t+2), ph3: B-k0(t+2)
            if (ph == 0) stage(tt + 1, 0, 1);
            else if (ph == 1) stage(tt + 1, 1, 1);
            else if (ph == 2) stage(tt + 2, 0, 0);
            else stage(tt + 2, 1, 0);
            __builtin_amdgcn_sched_barrier(0);
            __builtin_amdgcn_s_barrier();
            __builtin_amdgcn_sched_barrier(0);
            __builtin_amdgcn_s_setprio(1);
#pragma unroll
            for (int ii = 0; ii < 4; ++ii)
#pragma unroll
                for (int j = 0; j < 4; ++j)
                    acc[ih * 4 + ii][j] = __builtin_amdgcn_mfma_f32_16x16x32_bf16(
                        a[ii], b[j], acc[ih * 4 + ii][j], 0, 0, 0);
            __builtin_amdgcn_s_setprio(0);
            __builtin_amdgcn_sched_barrier(0);
            if (ph < 3) {
                __builtin_amdgcn_s_barrier();
                __builtin_amdgcn_sched_barrier(0);
            } else {
                // tile boundary: counted drain (never 0 mid-loop)
                if (tt + 2 < NT) asm volatile("s_waitcnt vmcnt(4)" ::: "memory");
                else             asm volatile("s_waitcnt vmcnt(0)" ::: "memory");
                __builtin_amdgcn_sched_barrier(0);
                __builtin_amdgcn_s_barrier();
                __builtin_amdgcn_sched_barrier(0);
            }
        }
    }

    // epilogue: row = bm + wm*128 + i*16 + (lane>>4)*4 + r, col = bn + wn*64 + j*16 + la
    const int colb = (int)bn + wn * 64 + la;
    float bj[4];
#pragma unroll
    for (int j = 0; j < 4; ++j) bj[j] = biasp[colb + j * 16];
#pragma unroll
    for (int i = 0; i < 8; ++i) {
        const int rb = (int)bm + wm * 128 + i * 16 + (lane >> 4) * 4;
#pragma unroll
        for (int j = 0; j < 4; ++j) {
            const int col = colb + j * 16;
#pragma unroll
            for (int r = 0; r < 4; ++r) {
                float v = acc[i][j][r] + bj[j];
                const size_t idx = (size_t)(rb + r) * N + col;
                if constexpr (EPI == 0) Cf[idx] = v;
                if constexpr (EPI == 1) Cf[idx] = tanhf(v);
                if constexpr (EPI == 2) Cb[idx] = bf16rne(tanhf(v));
                if constexpr (EPI == 3) {
                    float tv = tanhf(v);
                    uint16_t h = bf16rne(tv);
                    Chi[idx] = h;
                    Clo[idx] = bf16rne(tv - b2f(h));
                }
            }
        }
    }
}

// ---------------- 2-phase MFMA GEMM (verified R4 path, E2/D1/D2) ----------
template <int EPI, bool SPLIT>
__global__ __launch_bounds__(256) void gemm_mfma(
    const uint16_t* __restrict__ Ahi, const uint16_t* __restrict__ Alo,
    const uint16_t* __restrict__ Bhi, const uint16_t* __restrict__ Blo,
    const float* __restrict__ biasp,
    float* __restrict__ Cf, uint16_t* __restrict__ Cb,
    uint16_t* __restrict__ Chi, uint16_t* __restrict__ Clo,
    int M, int N, int K) {
    constexpr int AT = 128 * 32;
    __shared__ __align__(16) uint16_t As[SPLIT ? 2 * AT : AT];
    __shared__ __align__(16) uint16_t Bs[SPLIT ? 2 * AT : AT];

    const int tid = threadIdx.x;
    const int lane = tid & 63, wv = tid >> 6;
    const int wm = wv >> 1, wn = wv & 1;
    const int la = lane & 15, lk = lane >> 4;
    const size_t bm = (size_t)blockIdx.y * 128, bn = (size_t)blockIdx.x * 128;

    f32x4 acc[4][4];
#pragma unroll
    for (int i = 0; i < 4; ++i)
#pragma unroll
        for (int j = 0; j < 4; ++j) acc[i][j] = (f32x4){0.f, 0.f, 0.f, 0.f};

    for (int k0 = 0; k0 < K; k0 += 32) {
#pragma unroll
        for (int t = 0; t < 2; ++t) {
            const int cb_ = wv * 128 + t * 64;
            const int c = cb_ + lane;
            const int row = c >> 2, sub = c & 3;
            GLLDS(Ahi + (bm + row) * (size_t)K + k0 + sub * 8, &As[(size_t)cb_ * 8]);
            GLLDS(Bhi + (bn + row) * (size_t)K + k0 + sub * 8, &Bs[(size_t)cb_ * 8]);
            if constexpr (SPLIT) {
                GLLDS(Alo + (bm + row) * (size_t)K + k0 + sub * 8, &As[AT + (size_t)cb_ * 8]);
                GLLDS(Blo + (bn + row) * (size_t)K + k0 + sub * 8, &Bs[AT + (size_t)cb_ * 8]);
            }
        }
        __syncthreads();

        bf16x8 ah[4], bh[4], al[4], bl[4];
#pragma unroll
        for (int i = 0; i < 4; ++i) {
            const int ao = (wm * 64 + i * 16 + la) * 32 + lk * 8;
            const int bo = (wn * 64 + i * 16 + la) * 32 + lk * 8;
            ah[i] = *(const bf16x8*)&As[ao];
            bh[i] = *(const bf16x8*)&Bs[bo];
            if constexpr (SPLIT) {
                al[i] = *(const bf16x8*)&As[AT + ao];
                bl[i] = *(const bf16x8*)&Bs[AT + bo];
            }
        }
#pragma unroll
        for (int i = 0; i < 4; ++i)
#pragma unroll
            for (int j = 0; j < 4; ++j) {
                acc[i][j] = __builtin_amdgcn_mfma_f32_16x16x32_bf16(ah[i], bh[j], acc[i][j], 0, 0, 0);
                if constexpr (SPLIT) {
                    acc[i][j] = __builtin_amdgcn_mfma_f32_16x16x32_bf16(al[i], bh[j], acc[i][j], 0, 0, 0);
                    acc[i][j] = __builtin_amdgcn_mfma_f32_16x16x32_bf16(ah[i], bl[j], acc[i][j], 0, 0, 0);
                }
            }
        __syncthreads();
    }

    const int colb = (int)bn + wn * 64 + la;
    float bj[4];
#pragma unroll
    for (int j = 0; j < 4; ++j) bj[j] = biasp[colb + j * 16];
#pragma unroll
    for (int i = 0; i < 4; ++i) {
        const int rb = (int)bm + wm * 64 + i * 16 + lk * 4;
#pragma unroll
        for (int j = 0; j < 4; ++j) {
            const int col = colb + j * 16;
#pragma unroll
            for (int r = 0; r < 4; ++r) {
                float v = acc[i][j][r] + bj[j];
                const size_t idx = (size_t)(rb + r) * N + col;
                if constexpr (EPI == 0) Cf[idx] = v;
                if constexpr (EPI == 1) Cf[idx] = tanhf(v);
                if constexpr (EPI == 2) Cb[idx] = bf16rne(tanhf(v));
                if constexpr (EPI == 3) {
                    float tv = tanhf(v);
                    uint16_t h = bf16rne(tv);
                    Chi[idx] = h;
                    Clo[idx] = bf16rne(tv - b2f(h));
                }
            }
        }
    }
}

// ---------------- weight transpose+convert: W f32 [K+1][N] -> [N][K] bf16 ----
template <bool SPLIT>
__global__ __launch_bounds__(256) void wconv(const float* __restrict__ W,
                                             uint16_t* __restrict__ Thi,
                                             uint16_t* __restrict__ Tlo,
                                             int K, int N) {
    __shared__ float t[32][33];
    const int k0 = blockIdx.x * 32, n0 = blockIdx.y * 32;
    const int tid = threadIdx.x;
    {
        const int kl = tid >> 3, nq = tid & 7;
        float4 v = *(const float4*)(W + (size_t)(k0 + kl) * N + n0 + nq * 4);
        t[kl][nq * 4 + 0] = v.x;
        t[kl][nq * 4 + 1] = v.y;
        t[kl][nq * 4 + 2] = v.z;
        t[kl][nq * 4 + 3] = v.w;
    }
    __syncthreads();
    {
        const int nl = tid >> 3, kq = tid & 7;
        ushort4 hv, lv;
        float f0 = t[kq * 4 + 0][nl], f1 = t[kq * 4 + 1][nl];
        float f2 = t[kq * 4 + 2][nl], f3 = t[kq * 4 + 3][nl];
        hv.x = bf16rne(f0); hv.y = bf16rne(f1); hv.z = bf16rne(f2); hv.w = bf16rne(f3);
        *(ushort4*)(Thi + (size_t)(n0 + nl) * K + k0 + kq * 4) = hv;
        if constexpr (SPLIT) {
            lv.x = bf16rne(f0 - b2f(hv.x)); lv.y = bf16rne(f1 - b2f(hv.y));
            lv.z = bf16rne(f2 - b2f(hv.z)); lv.w = bf16rne(f3 - b2f(hv.w));
            *(ushort4*)(Tlo + (size_t)(n0 + nl) * K + k0 + kq * 4) = lv;
        }
    }
}

// ---------------- x -> hi/lo bf16 split (elementwise) ----------------
__global__ __launch_bounds__(256) void split_x(const float* __restrict__ x,
                                               uint16_t* __restrict__ hi,
                                               uint16_t* __restrict__ lo,
                                               size_t n4) {
    for (size_t i = (size_t)blockIdx.x * 256 + threadIdx.x; i < n4;
         i += (size_t)gridDim.x * 256) {
        float4 v = ((const float4*)x)[i];
        ushort4 h, l;
        h.x = bf16rne(v.x); l.x = bf16rne(v.x - b2f(h.x));
        h.y = bf16rne(v.y); l.y = bf16rne(v.y - b2f(h.y));
        h.z = bf16rne(v.z); l.z = bf16rne(v.z - b2f(h.z));
        h.w = bf16rne(v.w); l.w = bf16rne(v.w - b2f(h.w));
        ((ushort4*)hi)[i] = h;
        ((ushort4*)lo)[i] = l;
    }
}

// ---------------- VQ ----------------
template <bool YB16>
__global__ __launch_bounds__(256) void vq_kernel(
    const float* __restrict__ h, const float* __restrict__ cb,
    const uint32_t* __restrict__ nlp,
    float* __restrict__ yf, uint16_t* __restrict__ yb,
    uint32_t ka0, uint32_t ka1, uint32_t kb0, uint32_t kb1,
    uint32_t kc0, uint32_t kc1, uint32_t kd0, uint32_t kd1) {
    __shared__ float xs[DCODE];
    __shared__ float sred[NCODE];
    __shared__ int sidx[NCODE];

    const int b = blockIdx.x;
    const int chunk = blockIdx.y;
    const int c = threadIdx.x;

    if (c < DCODE) xs[c] = h[(size_t)b * NCODE + chunk * DCODE + c];
    __syncthreads();

    float dot = 0.f, x2 = 0.f, c2 = 0.f;
    const float* crow = cb + c * DCODE;
#pragma unroll 8
    for (int i = 0; i < DCODE; ++i) {
        float xv = xs[i], cv = crow[i];
        dot = fmaf(xv, cv, dot);
        x2 = fmaf(xv, xv, x2);
        c2 = fmaf(cv, cv, c2);
    }
    float d = sqrtf(fmaxf(x2 - 2.f * dot + c2, 0.f));
    float logit = -d * 0.125f;

    sred[c] = logit;
    __syncthreads();
    for (int s = 128; s > 0; s >>= 1) {
        if (c < s) sred[c] = fmaxf(sred[c], sred[c + s]);
        __syncthreads();
    }
    float mx = sred[0];
    __syncthreads();
    float e = expf(logit - mx);
    sred[c] = e;
    __syncthreads();
    for (int s = 128; s > 0; s >>= 1) {
        if (c < s) sred[c] = sred[c] + sred[c + s];
        __syncthreads();
    }
    float ssum = sred[0];
    __syncthreads();
    float r = e / ssum;

    int vi = (int)nlp[0];
    float noise_level = (vi >= -1000000 && vi <= 1000000)
                            ? (float)vi
                            : __uint_as_float(nlp[0]);

    // partitionable threefry: bits = o1 ^ o2, counter = (0, lin)
    uint32_t lin = (uint32_t)b * 256u + (uint32_t)c;
    uint32_t k0 = chunk == 0 ? ka0 : chunk == 1 ? kb0 : chunk == 2 ? kc0 : kd0;
    uint32_t k1 = chunk == 0 ? ka1 : chunk == 1 ? kb1 : chunk == 2 ? kc1 : kd1;
    uint32_t x0 = 0u, x1 = lin;
    tf2x32(k0, k1, x0, x1);
    uint32_t bits = x0 ^ x1;
    float noise = __uint_as_float((bits >> 9) | 0x3f800000u) - 1.0f;

    float score = r - noise_level * noise;

    sred[c] = score;
    sidx[c] = c;
    __syncthreads();
    for (int s = 128; s > 0; s >>= 1) {
        if (c < s) {
            float ov = sred[c + s];
            int oi = sidx[c + s];
            if (ov > sred[c] || (ov == sred[c] && oi < sidx[c])) {
                sred[c] = ov;
                sidx[c] = oi;
            }
        }
        __syncthreads();
    }
    int best = sidx[0];

    if (c < DCODE) {
        float v = cb[(size_t)best * DCODE + c];
        if constexpr (YB16)
            yb[(size_t)b * NCODE + chunk * DCODE + c] = bf16rne(v);
        else
            yf[(size_t)b * NCODE + chunk * DCODE + c] = v;
    }
}

// ---------------- fallback f32 GEMM (verified Round-4 path) ----------------
template <int BM, int BN, bool TANH>
__global__ __launch_bounds__(256) void gemm_f32(const float* __restrict__ A,
                                                const float* __restrict__ W,
                                                float* __restrict__ C,
                                                int M, int N, int K) {
    constexpr int BK = 16;
    constexpr int TM = BM / 16, TN = BN / 16;
    constexpr int GM = TM / 4, GN = TN / 4;
    constexpr int PA = BM + 4, PB = BN + 4;
    __shared__ float As[BK][PA];
    __shared__ float Bs[BK][PB];

    const int tid = threadIdx.x;
    const int tx = tid & 15, ty = tid >> 4;
    const size_t bm = (size_t)blockIdx.y * BM;
    const size_t bn = (size_t)blockIdx.x * BN;

    float acc[TM][TN];
#pragma unroll
    for (int i = 0; i < TM; ++i)
#pragma unroll
        for (int j = 0; j < TN; ++j) acc[i][j] = 0.f;

    for (int k0 = 0; k0 < K; k0 += BK) {
#pragma unroll
        for (int i = 0; i < BM * BK / 4 / 256; ++i) {
            int f4 = tid + i * 256;
            int row = f4 >> 2;
            int c4 = f4 & 3;
            float4 v = *reinterpret_cast<const float4*>(A + (bm + row) * K + k0 + c4 * 4);
            As[c4 * 4 + 0][row] = v.x;
            As[c4 * 4 + 1][row] = v.y;
            As[c4 * 4 + 2][row] = v.z;
            As[c4 * 4 + 3][row] = v.w;
        }
#pragma unroll
        for (int i = 0; i < BK * BN / 4 / 256; ++i) {
            int f4 = tid + i * 256;
            int row = f4 / (BN / 4);
            int c4 = f4 % (BN / 4);
            *reinterpret_cast<float4*>(&Bs[row][c4 * 4]) =
                *reinterpret_cast<const float4*>(W + (size_t)(k0 + row) * N + bn + c4 * 4);
        }
        __syncthreads();
#pragma unroll
        for (int k = 0; k < BK; ++k) {
            float4 af[GM], bf[GN];
#pragma unroll
            for (int g = 0; g < GM; ++g)
                af[g] = *reinterpret_cast<const float4*>(&As[k][g * 64 + ty * 4]);
#pragma unroll
            for (int g = 0; g < GN; ++g)
                bf[g] = *reinterpret_cast<const float4*>(&Bs[k][g * 64 + tx * 4]);
#pragma unroll
            for (int gm = 0; gm < GM; ++gm) {
                const float* ap = &af[gm].x;
#pragma unroll
                for (int r = 0; r < 4; ++r) {
#pragma unroll
                    for (int gn = 0; gn < GN; ++gn) {
                        const float* bp = &bf[gn].x;
#pragma unroll
                        for (int c = 0; c < 4; ++c)
                            acc[gm * 4 + r][gn * 4 + c] =
                                fmaf(ap[r], bp[c], acc[gm * 4 + r][gn * 4 + c]);
                    }
                }
            }
        }
        __syncthreads();
    }

#pragma unroll
    for (int gm = 0; gm < GM; ++gm) {
#pragma unroll
        for (int r = 0; r < 4; ++r) {
            size_t row = bm + gm * 64 + ty * 4 + r;
#pragma unroll
            for (int gn = 0; gn < GN; ++gn) {
                size_t col = bn + gn * 64 + tx * 4;
                float4 bias = *reinterpret_cast<const float4*>(W + (size_t)K * N + col);
                float4 o;
                o.x = acc[gm * 4 + r][gn * 4 + 0] + bias.x;
                o.y = acc[gm * 4 + r][gn * 4 + 1] + bias.y;
                o.z = acc[gm * 4 + r][gn * 4 + 2] + bias.z;
                o.w = acc[gm * 4 + r][gn * 4 + 3] + bias.w;
                if (TANH) {
                    o.x = tanhf(o.x); o.y = tanhf(o.y);
                    o.z = tanhf(o.z); o.w = tanhf(o.w);
                }
                *reinterpret_cast<float4*>(C + row * N + col) = o;
            }
        }
    }
}

// ---------------- launch ----------------
extern "C" void kernel_launch(void* const* d_in, const int* in_sizes, int n_in,
                              void* d_out, int out_size, void* d_ws, size_t ws_size,
                              hipStream_t stream) {
    const float* x   = (const float*)d_in[0];
    const float* w1e = (const float*)d_in[1];
    const float* w2e = (const float*)d_in[2];
    const float* w1d = (const float*)d_in[3];
    const float* w2d = (const float*)d_in[4];
    const float* cb1 = (const float*)d_in[5];
    const uint32_t* nl = (const uint32_t*)d_in[9];
    float* out = (float*)d_out;

    const int M = in_sizes[0] / IMG_DIM;  // 4096

    // VQ keys (host-side fold_in)
    uint32_t ks[4][2];
    for (int j = 1; j <= 4; ++j) {
        uint32_t a = 0u, bb = (uint32_t)j;
        tf2x32(0u, 12345u, a, bb);
        ks[j - 1][0] = a;
        ks[j - 1][1] = bb;
    }

    // ws layout (bytes), with time-aliasing:
    const size_t o_h1hi  = 0;           // 134217728  (later: h2 bf16)
    const size_t o_h1lo  = 134217728;   // 134217728
    const size_t o_w1ehi = 268435456;   // 100663296  (later: Wt2d)
    const size_t o_w1elo = 369098752;   // 100663296  (later: Wt1d)
    const size_t o_w2ehi = 469762048;   // 8388608
    const size_t o_w2elo = 478150656;   // 8388608
    const size_t o_h     = 486539264;   // 4194304
    const size_t o_y     = 490733568;   // 2097152
    const size_t o_xhi   = 492830720;   // 25165824
    const size_t o_xlo   = 517996544;   // 25165824
    const size_t NEED    = 543162368;

    uint8_t* ws = (uint8_t*)d_ws;

    if (ws_size >= NEED) {
        uint16_t* h1hi  = (uint16_t*)(ws + o_h1hi);
        uint16_t* h1lo  = (uint16_t*)(ws + o_h1lo);
        uint16_t* w1ehi = (uint16_t*)(ws + o_w1ehi);
        uint16_t* w1elo = (uint16_t*)(ws + o_w1elo);
        uint16_t* w2ehi = (uint16_t*)(ws + o_w2ehi);
        uint16_t* w2elo = (uint16_t*)(ws + o_w2elo);
        float*    hbuf  = (float*)(ws + o_h);
        uint16_t* ybuf  = (uint16_t*)(ws + o_y);
        uint16_t* xhi   = (uint16_t*)(ws + o_xhi);
        uint16_t* xlo   = (uint16_t*)(ws + o_xlo);
        uint16_t* wt2d  = (uint16_t*)(ws + o_w1ehi);  // alias after E1
        uint16_t* wt1d  = (uint16_t*)(ws + o_w1elo);  // alias after E1
        uint16_t* h2    = (uint16_t*)(ws + o_h1hi);   // alias after E2

        // prep
        split_x<<<2048, 256, 0, stream>>>(x, xhi, xlo, (size_t)M * IMG_DIM / 4);
        wconv<true><<<dim3(IMG_DIM / 32, HID / 32), 256, 0, stream>>>(w1e, w1ehi, w1elo, IMG_DIM, HID);
        wconv<true><<<dim3(HID / 32, NCODE / 32), 256, 0, stream>>>(w2e, w2ehi, w2elo, HID, NCODE);
        // E1 (8-phase, K'=3*3072 via segments): h1 = tanh(x @ w1e + b) -> bf16 hi/lo
        gemm8p<3, 48, 3><<<dim3(HID / 256, M / 256), 512, 0, stream>>>(
            xhi, xlo, xhi, w1ehi, w1ehi, w1elo,
            w1e + (size_t)IMG_DIM * HID,
            nullptr, nullptr, h1hi, h1lo, HID, IMG_DIM);
        // decoder weight conversions (into regions freed by E1)
        wconv<false><<<dim3(HID / 32, IMG_DIM / 32), 256, 0, stream>>>(w2d, wt2d, nullptr, HID, IMG_DIM);
        wconv<false><<<dim3(NCODE / 32, HID / 32), 256, 0, stream>>>(w1d, wt1d, nullptr, NCODE, HID);
        // E2: h = tanh(h1 @ w2e + b) -> f32
        gemm_mfma<1, true><<<dim3(NCODE / 128, M / 128), 256, 0, stream>>>(
            h1hi, h1lo, w2ehi, w2elo, w2e + (size_t)HID * NCODE,
            hbuf, nullptr, nullptr, nullptr, M, NCODE, HID);
        // VQ -> y bf16
        vq_kernel<true><<<dim3(M, 4), 256, 0, stream>>>(
            hbuf, cb1, nl, nullptr, ybuf,
            ks[0][0], ks[0][1], ks[1][0], ks[1][1],
            ks[2][0], ks[2][1], ks[3][0], ks[3][1]);
        // D1: h2 = tanh(y @ w1d + b) -> bf16
        gemm_mfma<2, false><<<dim3(HID / 128, M / 128), 256, 0, stream>>>(
            ybuf, nullptr, wt1d, nullptr, w1d + (size_t)NCODE * HID,
            nullptr, h2, nullptr, nullptr, M, HID, NCODE);
        // D2: out = h2 @ w2d + b -> f32
        gemm_mfma<0, false><<<dim3(IMG_DIM / 128, M / 128), 256, 0, stream>>>(
            h2, nullptr, wt2d, nullptr, w2d + (size_t)HID * IMG_DIM,
            out, nullptr, nullptr, nullptr, M, IMG_DIM, HID);
    } else {
        // fallback: verified f32 path
        float* h1 = (float*)d_ws;
        float* h  = h1 + (size_t)M * HID;
        float* yb = h + (size_t)M * NCODE;
        {
            dim3 g(HID / 128, M / 128);
            gemm_f32<128, 128, true><<<g, 256, 0, stream>>>(x, w1e, h1, M, HID, IMG_DIM);
        }
        {
            dim3 g(NCODE / 64, M / 64);
            gemm_f32<64, 64, true><<<g, 256, 0, stream>>>(h1, w2e, h, M, NCODE, HID);
        }
        vq_kernel<false><<<dim3(M, 4), 256, 0, stream>>>(
            h, cb1, nl, yb, nullptr,
            ks[0][0], ks[0][1], ks[1][0], ks[1][1],
            ks[2][0], ks[2][1], ks[3][0], ks[3][1]);
        {
            dim3 g(HID / 128, M / 128);
            gemm_f32<128, 128, true><<<g, 256, 0, stream>>>(yb, w1d, h1, M, HID, NCODE);
        }
        {
            dim3 g(IMG_DIM / 128, M / 128);
            gemm_f32<128, 128, false><<<g, 256, 0, stream>>>(h1, w2d, out, M, IMG_DIM, HID);
        }
    }
}

// Round 9
// 3609.308 us; speedup vs baseline: 1.1588x; 1.1588x over previous
//
#include <hip/hip_runtime.h>
#include <stdint.h>

// Codec forward. Round 8:
//  - gemm8p v2: minimal fencing (m141 lesson: sched_barrier spam = 40% loss),
//    explicit lgkmcnt(0)+sched_barrier per rule #18, hoisted stage addresses.
//  - E2 split-K x4 in one dispatch (grid.z), partials + bias in chunk0,
//    reduce+tanh fused into vq_kernel. Fixes 64-block under-occupancy.

#define IMG_DIM 3072
#define HID     16384
#define NCODE   256
#define DCODE   64

typedef short bf16x8 __attribute__((ext_vector_type(8)));
typedef float f32x4 __attribute__((ext_vector_type(4)));

__device__ __forceinline__ uint16_t bf16rne(float f) {
    uint32_t u = __float_as_uint(f);
    return (uint16_t)((u + 0x7fffu + ((u >> 16) & 1u)) >> 16);
}
__device__ __forceinline__ float b2f(uint16_t h) {
    return __uint_as_float((uint32_t)h << 16);
}

#define GLLDS(g, l)                                                        \
    __builtin_amdgcn_global_load_lds(                                      \
        (const __attribute__((address_space(1))) uint32_t*)(const void*)(g), \
        (__attribute__((address_space(3))) uint32_t*)(void*)(l), 16, 0, 0)

// ---------------- Threefry2x32 (matches jax/_src/prng.py) ----------------
__host__ __device__ __forceinline__ uint32_t rotl32(uint32_t v, int d) {
    return (v << d) | (v >> (32 - d));
}

__host__ __device__ __forceinline__ void tf2x32(uint32_t k0, uint32_t k1,
                                                uint32_t& x0, uint32_t& x1) {
    uint32_t k2 = k0 ^ k1 ^ 0x1BD11BDAu;
    x0 += k0; x1 += k1;
    x0 += x1; x1 = rotl32(x1, 13); x1 ^= x0;
    x0 += x1; x1 = rotl32(x1, 15); x1 ^= x0;
    x0 += x1; x1 = rotl32(x1, 26); x1 ^= x0;
    x0 += x1; x1 = rotl32(x1,  6); x1 ^= x0;
    x0 += k1; x1 += k2 + 1u;
    x0 += x1; x1 = rotl32(x1, 17); x1 ^= x0;
    x0 += x1; x1 = rotl32(x1, 29); x1 ^= x0;
    x0 += x1; x1 = rotl32(x1, 16); x1 ^= x0;
    x0 += x1; x1 = rotl32(x1, 24); x1 ^= x0;
    x0 += k2; x1 += k0 + 2u;
    x0 += x1; x1 = rotl32(x1, 13); x1 ^= x0;
    x0 += x1; x1 = rotl32(x1, 15); x1 ^= x0;
    x0 += x1; x1 = rotl32(x1, 26); x1 ^= x0;
    x0 += x1; x1 = rotl32(x1,  6); x1 ^= x0;
    x0 += k0; x1 += k1 + 3u;
    x0 += x1; x1 = rotl32(x1, 17); x1 ^= x0;
    x0 += x1; x1 = rotl32(x1, 29); x1 ^= x0;
    x0 += x1; x1 = rotl32(x1, 16); x1 ^= x0;
    x0 += x1; x1 = rotl32(x1, 24); x1 ^= x0;
    x0 += k1; x1 += k2 + 4u;
    x0 += x1; x1 = rotl32(x1, 13); x1 ^= x0;
    x0 += x1; x1 = rotl32(x1, 15); x1 ^= x0;
    x0 += x1; x1 = rotl32(x1, 26); x1 ^= x0;
    x0 += x1; x1 = rotl32(x1,  6); x1 ^= x0;
    x0 += k2; x1 += k0 + 5u;
}

// ---------------- 8-phase 256^2 MFMA GEMM v2 ----------------
template <int EPI, int TPS, int NSEG>
__global__ __launch_bounds__(512) void gemm8p(
    const uint16_t* __restrict__ a0, const uint16_t* __restrict__ a1,
    const uint16_t* __restrict__ a2,
    const uint16_t* __restrict__ b0, const uint16_t* __restrict__ b1,
    const uint16_t* __restrict__ b2,
    const float* __restrict__ biasp,
    float* __restrict__ Cf, uint16_t* __restrict__ Cb,
    uint16_t* __restrict__ Chi, uint16_t* __restrict__ Clo,
    int N, int Kseg) {
    __shared__ __align__(16) uint8_t lds[131072];
    constexpr int NT = TPS * NSEG;

    const int tid = threadIdx.x;
    const int lane = tid & 63, wv = tid >> 6;
    const int wm = wv >> 2, wn = wv & 3;
    const int la = lane & 15;
    const int lkb = (lane >> 4) << 4;

    const int nbx = gridDim.x;
    const int nwg = nbx * gridDim.y;
    int flat = blockIdx.y * nbx + blockIdx.x;
    if ((nwg & 7) == 0) flat = (flat & 7) * (nwg >> 3) + (flat >> 3);
    const size_t bm = (size_t)(flat / nbx) * 256;
    const size_t bn = (size_t)(flat % nbx) * 256;

    auto swz = [](int r) -> int {
        return (((r >> 1) & 1) << 5) | (((r >> 2) & 1) << 4);
    };

    // per-lane invariant stage offsets (element units, minus tloc*64+kh*32)
    size_t sAb[2], sBb[2];
    int ldsub[2];
#pragma unroll
    for (int p = 0; p < 2; ++p) {
        const int off = (p * 512 + tid) * 16;
        const int r = off >> 6;
        const int logc = (off & 63) ^ swz(r);
        sAb[p] = (bm + r) * (size_t)Kseg + (logc >> 1);
        sBb[p] = (bn + r) * (size_t)Kseg + (logc >> 1);
        ldsub[p] = p * 8192 + wv * 1024;
    }

    auto stage = [&](int tt, int mat, int kh) {
        if (tt >= NT) return;
        const int s = tt / TPS;
        const int tloc = tt - s * TPS;
        const uint16_t* mb;
        const size_t* sb;
        if (mat == 0) { mb = (s == 0 ? a0 : (s == 1 ? a1 : a2)); sb = sAb; }
        else          { mb = (s == 0 ? b0 : (s == 1 ? b1 : b2)); sb = sBb; }
        const int ub = mat * 65536 + (tt & 1) * 32768 + kh * 16384;
        const int kadd = tloc * 64 + kh * 32;
#pragma unroll
        for (int p = 0; p < 2; ++p)
            GLLDS(mb + sb[p] + kadd, lds + ub + ldsub[p]);
    };

    // per-lane invariant read offsets (swz depends only on la bits 1..2)
    int aoff[8], boff[4];
#pragma unroll
    for (int i = 0; i < 8; ++i)
        aoff[i] = (wm * 128 + i * 16 + la) * 64 + (lkb ^ swz(la));
#pragma unroll
    for (int j = 0; j < 4; ++j)
        boff[j] = 65536 + (wn * 64 + j * 16 + la) * 64 + (lkb ^ swz(la));

    f32x4 acc[8][4];
#pragma unroll
    for (int i = 0; i < 8; ++i)
#pragma unroll
        for (int j = 0; j < 4; ++j) acc[i][j] = (f32x4){0.f, 0.f, 0.f, 0.f};

    // prologue
    stage(0, 0, 0); stage(0, 1, 0); stage(0, 0, 1); stage(0, 1, 1);
    stage(1, 0, 0); stage(1, 1, 0);
    __builtin_amdgcn_sched_barrier(0);
    if (NT > 1) asm volatile("s_waitcnt vmcnt(4)" ::: "memory");
    else        asm volatile("s_waitcnt vmcnt(0)" ::: "memory");
    __builtin_amdgcn_s_barrier();
    __builtin_amdgcn_sched_barrier(0);

    for (int tt = 0; tt < NT; ++tt) {
        const int buf = tt & 1;
        const int lb = buf * 32768;
        bf16x8 b[4];
#pragma unroll
        for (int ph = 0; ph < 4; ++ph) {
            const int ks = ph >> 1, ih = ph & 1;
            bf16x8 a[4];
#pragma unroll
            for (int ii = 0; ii < 4; ++ii)
                a[ii] = *(const bf16x8*)(lds + lb + ks * 16384 + aoff[ih * 4 + ii]);
            if (ih == 0) {
#pragma unroll
                for (int j = 0; j < 4; ++j)
                    b[j] = *(const bf16x8*)(lds + lb + ks * 16384 + boff[j]);
            }
            if (ph == 0) stage(tt + 1, 0, 1);
            else if (ph == 1) stage(tt + 1, 1, 1);
            else if (ph == 2) stage(tt + 2, 0, 0);
            else stage(tt + 2, 1, 0);
            __builtin_amdgcn_sched_barrier(0);
            __builtin_amdgcn_s_barrier();
            asm volatile("s_waitcnt lgkmcnt(0)" ::: "memory");
            __builtin_amdgcn_sched_barrier(0);
            __builtin_amdgcn_s_setprio(1);
#pragma unroll
            for (int ii = 0; ii < 4; ++ii)
#pragma unroll
                for (int j = 0; j < 4; ++j)
                    acc[ih * 4 + ii][j] = __builtin_amdgcn_mfma_f32_16x16x32_bf16(
                        a[ii], b[j], acc[ih * 4 + ii][j], 0, 0, 0);
            __builtin_amdgcn_s_setprio(0);
            if (ph < 3) {
                __builtin_amdgcn_s_barrier();
            } else {
                if (tt + 2 < NT) asm volatile("s_waitcnt vmcnt(4)" ::: "memory");
                else             asm volatile("s_waitcnt vmcnt(0)" ::: "memory");
                __builtin_amdgcn_s_barrier();
                __builtin_amdgcn_sched_barrier(0);
            }
        }
    }

    const int colb = (int)bn + wn * 64 + la;
    float bj[4];
#pragma unroll
    for (int j = 0; j < 4; ++j) bj[j] = biasp[colb + j * 16];
#pragma unroll
    for (int i = 0; i < 8; ++i) {
        const int rb = (int)bm + wm * 128 + i * 16 + (lane >> 4) * 4;
#pragma unroll
        for (int j = 0; j < 4; ++j) {
            const int col = colb + j * 16;
#pragma unroll
            for (int r = 0; r < 4; ++r) {
                float v = acc[i][j][r] + bj[j];
                const size_t idx = (size_t)(rb + r) * N + col;
                if constexpr (EPI == 0) Cf[idx] = v;
                if constexpr (EPI == 1) Cf[idx] = tanhf(v);
                if constexpr (EPI == 2) Cb[idx] = bf16rne(tanhf(v));
                if constexpr (EPI == 3) {
                    float tv = tanhf(v);
                    uint16_t h = bf16rne(tv);
                    Chi[idx] = h;
                    Clo[idx] = bf16rne(tv - b2f(h));
                }
            }
        }
    }
}

// ---------------- 2-phase MFMA GEMM (lda/ldb + optional K-split) ----------
// KSPLIT: blockIdx.z = K-chunk; A/B advance kc*K; Cf advances kc*M*N;
//         bias added only for kc==0.
template <int EPI, bool SPLIT, bool KSPLIT>
__global__ __launch_bounds__(256) void gemm_mfma(
    const uint16_t* __restrict__ Ahi, const uint16_t* __restrict__ Alo,
    const uint16_t* __restrict__ Bhi, const uint16_t* __restrict__ Blo,
    const float* __restrict__ biasp,
    float* __restrict__ Cf, uint16_t* __restrict__ Cb,
    uint16_t* __restrict__ Chi, uint16_t* __restrict__ Clo,
    int M, int N, int K, int lda, int ldb) {
    constexpr int AT = 128 * 32;
    __shared__ __align__(16) uint16_t As[SPLIT ? 2 * AT : AT];
    __shared__ __align__(16) uint16_t Bs[SPLIT ? 2 * AT : AT];

    const int tid = threadIdx.x;
    const int lane = tid & 63, wv = tid >> 6;
    const int wm = wv >> 1, wn = wv & 1;
    const int la = lane & 15, lk = lane >> 4;
    const size_t bm = (size_t)blockIdx.y * 128, bn = (size_t)blockIdx.x * 128;

    int kc = 0;
    if constexpr (KSPLIT) {
        kc = blockIdx.z;
        const size_t ko = (size_t)kc * K;
        Ahi += ko;
        Bhi += ko;
        if constexpr (SPLIT) { Alo += ko; Blo += ko; }
        Cf += (size_t)kc * M * N;
    }

    f32x4 acc[4][4];
#pragma unroll
    for (int i = 0; i < 4; ++i)
#pragma unroll
        for (int j = 0; j < 4; ++j) acc[i][j] = (f32x4){0.f, 0.f, 0.f, 0.f};

    for (int k0 = 0; k0 < K; k0 += 32) {
#pragma unroll
        for (int t = 0; t < 2; ++t) {
            const int cb_ = wv * 128 + t * 64;
            const int c = cb_ + lane;
            const int row = c >> 2, sub = c & 3;
            GLLDS(Ahi + (bm + row) * (size_t)lda + k0 + sub * 8, &As[(size_t)cb_ * 8]);
            GLLDS(Bhi + (bn + row) * (size_t)ldb + k0 + sub * 8, &Bs[(size_t)cb_ * 8]);
            if constexpr (SPLIT) {
                GLLDS(Alo + (bm + row) * (size_t)lda + k0 + sub * 8, &As[AT + (size_t)cb_ * 8]);
                GLLDS(Blo + (bn + row) * (size_t)ldb + k0 + sub * 8, &Bs[AT + (size_t)cb_ * 8]);
            }
        }
        __syncthreads();

        bf16x8 ah[4], bh[4], al[4], bl[4];
#pragma unroll
        for (int i = 0; i < 4; ++i) {
            const int ao = (wm * 64 + i * 16 + la) * 32 + lk * 8;
            const int bo = (wn * 64 + i * 16 + la) * 32 + lk * 8;
            ah[i] = *(const bf16x8*)&As[ao];
            bh[i] = *(const bf16x8*)&Bs[bo];
            if constexpr (SPLIT) {
                al[i] = *(const bf16x8*)&As[AT + ao];
                bl[i] = *(const bf16x8*)&Bs[AT + bo];
            }
        }
#pragma unroll
        for (int i = 0; i < 4; ++i)
#pragma unroll
            for (int j = 0; j < 4; ++j) {
                acc[i][j] = __builtin_amdgcn_mfma_f32_16x16x32_bf16(ah[i], bh[j], acc[i][j], 0, 0, 0);
                if constexpr (SPLIT) {
                    acc[i][j] = __builtin_amdgcn_mfma_f32_16x16x32_bf16(al[i], bh[j], acc[i][j], 0, 0, 0);
                    acc[i][j] = __builtin_amdgcn_mfma_f32_16x16x32_bf16(ah[i], bl[j], acc[i][j], 0, 0, 0);
                }
            }
        __syncthreads();
    }

    const int colb = (int)bn + wn * 64 + la;
    float bj[4];
#pragma unroll
    for (int j = 0; j < 4; ++j) bj[j] = biasp[colb + j * 16];
    if constexpr (KSPLIT) {
        if (kc != 0) {
#pragma unroll
            for (int j = 0; j < 4; ++j) bj[j] = 0.f;
        }
    }
#pragma unroll
    for (int i = 0; i < 4; ++i) {
        const int rb = (int)bm + wm * 64 + i * 16 + lk * 4;
#pragma unroll
        for (int j = 0; j < 4; ++j) {
            const int col = colb + j * 16;
#pragma unroll
            for (int r = 0; r < 4; ++r) {
                float v = acc[i][j][r] + bj[j];
                const size_t idx = (size_t)(rb + r) * N + col;
                if constexpr (EPI == 0) Cf[idx] = v;
                if constexpr (EPI == 1) Cf[idx] = tanhf(v);
                if constexpr (EPI == 2) Cb[idx] = bf16rne(tanhf(v));
                if constexpr (EPI == 3) {
                    float tv = tanhf(v);
                    uint16_t h = bf16rne(tv);
                    Chi[idx] = h;
                    Clo[idx] = bf16rne(tv - b2f(h));
                }
            }
        }
    }
}

// ---------------- weight transpose+convert ----------------
template <bool SPLIT>
__global__ __launch_bounds__(256) void wconv(const float* __restrict__ W,
                                             uint16_t* __restrict__ Thi,
                                             uint16_t* __restrict__ Tlo,
                                             int K, int N) {
    __shared__ float t[32][33];
    const int k0 = blockIdx.x * 32, n0 = blockIdx.y * 32;
    const int tid = threadIdx.x;
    {
        const int kl = tid >> 3, nq = tid & 7;
        float4 v = *(const float4*)(W + (size_t)(k0 + kl) * N + n0 + nq * 4);
        t[kl][nq * 4 + 0] = v.x;
        t[kl][nq * 4 + 1] = v.y;
        t[kl][nq * 4 + 2] = v.z;
        t[kl][nq * 4 + 3] = v.w;
    }
    __syncthreads();
    {
        const int nl = tid >> 3, kq = tid & 7;
        ushort4 hv, lv;
        float f0 = t[kq * 4 + 0][nl], f1 = t[kq * 4 + 1][nl];
        float f2 = t[kq * 4 + 2][nl], f3 = t[kq * 4 + 3][nl];
        hv.x = bf16rne(f0); hv.y = bf16rne(f1); hv.z = bf16rne(f2); hv.w = bf16rne(f3);
        *(ushort4*)(Thi + (size_t)(n0 + nl) * K + k0 + kq * 4) = hv;
        if constexpr (SPLIT) {
            lv.x = bf16rne(f0 - b2f(hv.x)); lv.y = bf16rne(f1 - b2f(hv.y));
            lv.z = bf16rne(f2 - b2f(hv.z)); lv.w = bf16rne(f3 - b2f(hv.w));
            *(ushort4*)(Tlo + (size_t)(n0 + nl) * K + k0 + kq * 4) = lv;
        }
    }
}

// ---------------- x -> hi/lo bf16 split ----------------
__global__ __launch_bounds__(256) void split_x(const float* __restrict__ x,
                                               uint16_t* __restrict__ hi,
                                               uint16_t* __restrict__ lo,
                                               size_t n4) {
    for (size_t i = (size_t)blockIdx.x * 256 + threadIdx.x; i < n4;
         i += (size_t)gridDim.x * 256) {
        float4 v = ((const float4*)x)[i];
        ushort4 h, l;
        h.x = bf16rne(v.x); l.x = bf16rne(v.x - b2f(h.x));
        h.y = bf16rne(v.y); l.y = bf16rne(v.y - b2f(h.y));
        h.z = bf16rne(v.z); l.z = bf16rne(v.z - b2f(h.z));
        h.w = bf16rne(v.w); l.w = bf16rne(v.w - b2f(h.w));
        ((ushort4*)hi)[i] = h;
        ((ushort4*)lo)[i] = l;
    }
}

// ---------------- VQ (NPART>0: h = partials, sum+tanh fused) -------------
template <bool YB16, int NPART>
__global__ __launch_bounds__(256) void vq_kernel(
    const float* __restrict__ h, size_t pstride,
    const float* __restrict__ cb,
    const uint32_t* __restrict__ nlp,
    float* __restrict__ yf, uint16_t* __restrict__ yb,
    uint32_t ka0, uint32_t ka1, uint32_t kb0, uint32_t kb1,
    uint32_t kc0, uint32_t kc1, uint32_t kd0, uint32_t kd1) {
    __shared__ float xs[DCODE];
    __shared__ float sred[NCODE];
    __shared__ int sidx[NCODE];

    const int b = blockIdx.x;
    const int chunk = blockIdx.y;
    const int c = threadIdx.x;

    if (c < DCODE) {
        const size_t idx = (size_t)b * NCODE + chunk * DCODE + c;
        if constexpr (NPART > 0) {
            float z = h[idx];
#pragma unroll
            for (int p = 1; p < NPART; ++p) z += h[(size_t)p * pstride + idx];
            xs[c] = tanhf(z);
        } else {
            xs[c] = h[idx];
        }
    }
    __syncthreads();

    float dot = 0.f, x2 = 0.f, c2 = 0.f;
    const float* crow = cb + c * DCODE;
#pragma unroll 8
    for (int i = 0; i < DCODE; ++i) {
        float xv = xs[i], cv = crow[i];
        dot = fmaf(xv, cv, dot);
        x2 = fmaf(xv, xv, x2);
        c2 = fmaf(cv, cv, c2);
    }
    float d = sqrtf(fmaxf(x2 - 2.f * dot + c2, 0.f));
    float logit = -d * 0.125f;

    sred[c] = logit;
    __syncthreads();
    for (int s = 128; s > 0; s >>= 1) {
        if (c < s) sred[c] = fmaxf(sred[c], sred[c + s]);
        __syncthreads();
    }
    float mx = sred[0];
    __syncthreads();
    float e = expf(logit - mx);
    sred[c] = e;
    __syncthreads();
    for (int s = 128; s > 0; s >>= 1) {
        if (c < s) sred[c] = sred[c] + sred[c + s];
        __syncthreads();
    }
    float ssum = sred[0];
    __syncthreads();
    float r = e / ssum;

    int vi = (int)nlp[0];
    float noise_level = (vi >= -1000000 && vi <= 1000000)
                            ? (float)vi
                            : __uint_as_float(nlp[0]);

    uint32_t lin = (uint32_t)b * 256u + (uint32_t)c;
    uint32_t k0 = chunk == 0 ? ka0 : chunk == 1 ? kb0 : chunk == 2 ? kc0 : kd0;
    uint32_t k1 = chunk == 0 ? ka1 : chunk == 1 ? kb1 : chunk == 2 ? kc1 : kd1;
    uint32_t x0 = 0u, x1 = lin;
    tf2x32(k0, k1, x0, x1);
    uint32_t bits = x0 ^ x1;
    float noise = __uint_as_float((bits >> 9) | 0x3f800000u) - 1.0f;

    float score = r - noise_level * noise;

    sred[c] = score;
    sidx[c] = c;
    __syncthreads();
    for (int s = 128; s > 0; s >>= 1) {
        if (c < s) {
            float ov = sred[c + s];
            int oi = sidx[c + s];
            if (ov > sred[c] || (ov == sred[c] && oi < sidx[c])) {
                sred[c] = ov;
                sidx[c] = oi;
            }
        }
        __syncthreads();
    }
    int best = sidx[0];

    if (c < DCODE) {
        float v = cb[(size_t)best * DCODE + c];
        if constexpr (YB16)
            yb[(size_t)b * NCODE + chunk * DCODE + c] = bf16rne(v);
        else
            yf[(size_t)b * NCODE + chunk * DCODE + c] = v;
    }
}

// ---------------- fallback f32 GEMM (verified Round-4 path) ----------------
template <int BM, int BN, bool TANH>
__global__ __launch_bounds__(256) void gemm_f32(const float* __restrict__ A,
                                                const float* __restrict__ W,
                                                float* __restrict__ C,
                                                int M, int N, int K) {
    constexpr int BK = 16;
    constexpr int TM = BM / 16, TN = BN / 16;
    constexpr int GM = TM / 4, GN = TN / 4;
    constexpr int PA = BM + 4, PB = BN + 4;
    __shared__ float As[BK][PA];
    __shared__ float Bs[BK][PB];

    const int tid = threadIdx.x;
    const int tx = tid & 15, ty = tid >> 4;
    const size_t bm = (size_t)blockIdx.y * BM;
    const size_t bn = (size_t)blockIdx.x * BN;

    float acc[TM][TN];
#pragma unroll
    for (int i = 0; i < TM; ++i)
#pragma unroll
        for (int j = 0; j < TN; ++j) acc[i][j] = 0.f;

    for (int k0 = 0; k0 < K; k0 += BK) {
#pragma unroll
        for (int i = 0; i < BM * BK / 4 / 256; ++i) {
            int f4 = tid + i * 256;
            int row = f4 >> 2;
            int c4 = f4 & 3;
            float4 v = *reinterpret_cast<const float4*>(A + (bm + row) * K + k0 + c4 * 4);
            As[c4 * 4 + 0][row] = v.x;
            As[c4 * 4 + 1][row] = v.y;
            As[c4 * 4 + 2][row] = v.z;
            As[c4 * 4 + 3][row] = v.w;
        }
#pragma unroll
        for (int i = 0; i < BK * BN / 4 / 256; ++i) {
            int f4 = tid + i * 256;
            int row = f4 / (BN / 4);
            int c4 = f4 % (BN / 4);
            *reinterpret_cast<float4*>(&Bs[row][c4 * 4]) =
                *reinterpret_cast<const float4*>(W + (size_t)(k0 + row) * N + bn + c4 * 4);
        }
        __syncthreads();
#pragma unroll
        for (int k = 0; k < BK; ++k) {
            float4 af[GM], bf[GN];
#pragma unroll
            for (int g = 0; g < GM; ++g)
                af[g] = *reinterpret_cast<const float4*>(&As[k][g * 64 + ty * 4]);
#pragma unroll
            for (int g = 0; g < GN; ++g)
                bf[g] = *reinterpret_cast<const float4*>(&Bs[k][g * 64 + tx * 4]);
#pragma unroll
            for (int gm = 0; gm < GM; ++gm) {
                const float* ap = &af[gm].x;
#pragma unroll
                for (int r = 0; r < 4; ++r) {
#pragma unroll
                    for (int gn = 0; gn < GN; ++gn) {
                        const float* bp = &bf[gn].x;
#pragma unroll
                        for (int c = 0; c < 4; ++c)
                            acc[gm * 4 + r][gn * 4 + c] =
                                fmaf(ap[r], bp[c], acc[gm * 4 + r][gn * 4 + c]);
                    }
                }
            }
        }
        __syncthreads();
    }

#pragma unroll
    for (int gm = 0; gm < GM; ++gm) {
#pragma unroll
        for (int r = 0; r < 4; ++r) {
            size_t row = bm + gm * 64 + ty * 4 + r;
#pragma unroll
            for (int gn = 0; gn < GN; ++gn) {
                size_t col = bn + gn * 64 + tx * 4;
                float4 bias = *reinterpret_cast<const float4*>(W + (size_t)K * N + col);
                float4 o;
                o.x = acc[gm * 4 + r][gn * 4 + 0] + bias.x;
                o.y = acc[gm * 4 + r][gn * 4 + 1] + bias.y;
                o.z = acc[gm * 4 + r][gn * 4 + 2] + bias.z;
                o.w = acc[gm * 4 + r][gn * 4 + 3] + bias.w;
                if (TANH) {
                    o.x = tanhf(o.x); o.y = tanhf(o.y);
                    o.z = tanhf(o.z); o.w = tanhf(o.w);
                }
                *reinterpret_cast<float4*>(C + row * N + col) = o;
            }
        }
    }
}

// ---------------- launch ----------------
extern "C" void kernel_launch(void* const* d_in, const int* in_sizes, int n_in,
                              void* d_out, int out_size, void* d_ws, size_t ws_size,
                              hipStream_t stream) {
    const float* x   = (const float*)d_in[0];
    const float* w1e = (const float*)d_in[1];
    const float* w2e = (const float*)d_in[2];
    const float* w1d = (const float*)d_in[3];
    const float* w2d = (const float*)d_in[4];
    const float* cb1 = (const float*)d_in[5];
    const uint32_t* nl = (const uint32_t*)d_in[9];
    float* out = (float*)d_out;

    const int M = in_sizes[0] / IMG_DIM;  // 4096

    uint32_t ks[4][2];
    for (int j = 1; j <= 4; ++j) {
        uint32_t a = 0u, bb = (uint32_t)j;
        tf2x32(0u, 12345u, a, bb);
        ks[j - 1][0] = a;
        ks[j - 1][1] = bb;
    }

    // ws layout (bytes), with time-aliasing:
    const size_t o_h1hi  = 0;           // 134217728  (later: h2 bf16)
    const size_t o_h1lo  = 134217728;   // 134217728
    const size_t o_w1ehi = 268435456;   // 100663296  (later: Wt2d)
    const size_t o_w1elo = 369098752;   // 100663296  (later: Wt1d)
    const size_t o_w2ehi = 469762048;   // 8388608
    const size_t o_w2elo = 478150656;   // 8388608
    const size_t o_h     = 486539264;   // 4194304 (unused in main path now)
    const size_t o_y     = 490733568;   // 2097152
    const size_t o_xhi   = 492830720;   // 25165824 (aliased: E2 partials, 16MB)
    const size_t o_xlo   = 517996544;   // 25165824
    const size_t NEED    = 543162368;

    uint8_t* ws = (uint8_t*)d_ws;

    if (ws_size >= NEED) {
        uint16_t* h1hi  = (uint16_t*)(ws + o_h1hi);
        uint16_t* h1lo  = (uint16_t*)(ws + o_h1lo);
        uint16_t* w1ehi = (uint16_t*)(ws + o_w1ehi);
        uint16_t* w1elo = (uint16_t*)(ws + o_w1elo);
        uint16_t* w2ehi = (uint16_t*)(ws + o_w2ehi);
        uint16_t* w2elo = (uint16_t*)(ws + o_w2elo);
        uint16_t* ybuf  = (uint16_t*)(ws + o_y);
        uint16_t* xhi   = (uint16_t*)(ws + o_xhi);
        uint16_t* xlo   = (uint16_t*)(ws + o_xlo);
        uint16_t* wt2d  = (uint16_t*)(ws + o_w1ehi);  // alias after E1
        uint16_t* wt1d  = (uint16_t*)(ws + o_w1elo);  // alias after E1
        uint16_t* h2    = (uint16_t*)(ws + o_h1hi);   // alias after E2
        float*    e2p   = (float*)(ws + o_xhi);       // alias after E1 (16MB)

        // prep
        split_x<<<2048, 256, 0, stream>>>(x, xhi, xlo, (size_t)M * IMG_DIM / 4);
        wconv<true><<<dim3(IMG_DIM / 32, HID / 32), 256, 0, stream>>>(w1e, w1ehi, w1elo, IMG_DIM, HID);
        wconv<true><<<dim3(HID / 32, NCODE / 32), 256, 0, stream>>>(w2e, w2ehi, w2elo, HID, NCODE);
        // E1 (8-phase v2): h1 = tanh(x @ w1e + b) -> bf16 hi/lo
        gemm8p<3, 48, 3><<<dim3(HID / 256, M / 256), 512, 0, stream>>>(
            xhi, xlo, xhi, w1ehi, w1ehi, w1elo,
            w1e + (size_t)IMG_DIM * HID,
            nullptr, nullptr, h1hi, h1lo, HID, IMG_DIM);
        // decoder weight conversions (into regions freed by E1)
        wconv<false><<<dim3(HID / 32, IMG_DIM / 32), 256, 0, stream>>>(w2d, wt2d, nullptr, HID, IMG_DIM);
        wconv<false><<<dim3(NCODE / 32, HID / 32), 256, 0, stream>>>(w1d, wt1d, nullptr, NCODE, HID);
        // E2 split-K x4 (one dispatch, 256 blocks): partials into e2p
        gemm_mfma<0, true, true><<<dim3(NCODE / 128, M / 128, 4), 256, 0, stream>>>(
            h1hi, h1lo, w2ehi, w2elo, w2e + (size_t)HID * NCODE,
            e2p, nullptr, nullptr, nullptr, M, NCODE, HID / 4, HID, HID);
        // VQ (fused partial-sum + tanh) -> y bf16
        vq_kernel<true, 4><<<dim3(M, 4), 256, 0, stream>>>(
            e2p, (size_t)M * NCODE, cb1, nl, nullptr, ybuf,
            ks[0][0], ks[0][1], ks[1][0], ks[1][1],
            ks[2][0], ks[2][1], ks[3][0], ks[3][1]);
        // D1: h2 = tanh(y @ w1d + b) -> bf16
        gemm_mfma<2, false, false><<<dim3(HID / 128, M / 128), 256, 0, stream>>>(
            ybuf, nullptr, wt1d, nullptr, w1d + (size_t)NCODE * HID,
            nullptr, h2, nullptr, nullptr, M, HID, NCODE, NCODE, NCODE);
        // D2: out = h2 @ w2d + b -> f32
        gemm_mfma<0, false, false><<<dim3(IMG_DIM / 128, M / 128), 256, 0, stream>>>(
            h2, nullptr, wt2d, nullptr, w2d + (size_t)HID * IMG_DIM,
            out, nullptr, nullptr, nullptr, M, IMG_DIM, HID, HID, HID);
    } else {
        // fallback: verified f32 path
        float* h1 = (float*)d_ws;
        float* h  = h1 + (size_t)M * HID;
        float* yb = h + (size_t)M * NCODE;
        {
            dim3 g(HID / 128, M / 128);
            gemm_f32<128, 128, true><<<g, 256, 0, stream>>>(x, w1e, h1, M, HID, IMG_DIM);
        }
        {
            dim3 g(NCODE / 64, M / 64);
            gemm_f32<64, 64, true><<<g, 256, 0, stream>>>(h1, w2e, h, M, NCODE, HID);
        }
        vq_kernel<false, 0><<<dim3(M, 4), 256, 0, stream>>>(
            h, 0, cb1, nl, yb, nullptr,
            ks[0][0], ks[0][1], ks[1][0], ks[1][1],
            ks[2][0], ks[2][1], ks[3][0], ks[3][1]);
        {
            dim3 g(HID / 128, M / 128);
            gemm_f32<128, 128, true><<<g, 256, 0, stream>>>(yb, w1d, h1, M, HID, NCODE);
        }
        {
            dim3 g(IMG_DIM / 128, M / 128);
            gemm_f32<128, 128, false><<<g, 256, 0, stream>>>(h1, w2d, out, M, IMG_DIM, HID);
        }
    }
}

// Round 12
// 2550.515 us; speedup vs baseline: 1.6399x; 1.4151x over previous
//
#include <hip/hip_runtime.h>
#include <stdint.h>

// Codec forward. Round 9: revert E1 to the PROVEN 2-phase MFMA kernel
// (871 TF, m97-structure ceiling; two 8-phase ports failed to beat it and
// are abandoned). Keep R8's E2 split-K x4 + fused partial-sum VQ.
//   E1: bf16x2-split 3-term MFMA (argmax-safe)     [2-phase, 1024 blocks]
//   E2: bf16x2-split, split-K x4, partials->VQ     [256 blocks]
//   D1/D2: plain bf16 MFMA                          [2-phase]
// Rounds 10-11: resubmit unchanged (container infra failures, no signal).

#define IMG_DIM 3072
#define HID     16384
#define NCODE   256
#define DCODE   64

typedef short bf16x8 __attribute__((ext_vector_type(8)));
typedef float f32x4 __attribute__((ext_vector_type(4)));

__device__ __forceinline__ uint16_t bf16rne(float f) {
    uint32_t u = __float_as_uint(f);
    return (uint16_t)((u + 0x7fffu + ((u >> 16) & 1u)) >> 16);
}
__device__ __forceinline__ float b2f(uint16_t h) {
    return __uint_as_float((uint32_t)h << 16);
}

#define GLLDS(g, l)                                                        \
    __builtin_amdgcn_global_load_lds(                                      \
        (const __attribute__((address_space(1))) uint32_t*)(const void*)(g), \
        (__attribute__((address_space(3))) uint32_t*)(void*)(l), 16, 0, 0)

// ---------------- Threefry2x32 (matches jax/_src/prng.py) ----------------
__host__ __device__ __forceinline__ uint32_t rotl32(uint32_t v, int d) {
    return (v << d) | (v >> (32 - d));
}

__host__ __device__ __forceinline__ void tf2x32(uint32_t k0, uint32_t k1,
                                                uint32_t& x0, uint32_t& x1) {
    uint32_t k2 = k0 ^ k1 ^ 0x1BD11BDAu;
    x0 += k0; x1 += k1;
    x0 += x1; x1 = rotl32(x1, 13); x1 ^= x0;
    x0 += x1; x1 = rotl32(x1, 15); x1 ^= x0;
    x0 += x1; x1 = rotl32(x1, 26); x1 ^= x0;
    x0 += x1; x1 = rotl32(x1,  6); x1 ^= x0;
    x0 += k1; x1 += k2 + 1u;
    x0 += x1; x1 = rotl32(x1, 17); x1 ^= x0;
    x0 += x1; x1 = rotl32(x1, 29); x1 ^= x0;
    x0 += x1; x1 = rotl32(x1, 16); x1 ^= x0;
    x0 += x1; x1 = rotl32(x1, 24); x1 ^= x0;
    x0 += k2; x1 += k0 + 2u;
    x0 += x1; x1 = rotl32(x1, 13); x1 ^= x0;
    x0 += x1; x1 = rotl32(x1, 15); x1 ^= x0;
    x0 += x1; x1 = rotl32(x1, 26); x1 ^= x0;
    x0 += x1; x1 = rotl32(x1,  6); x1 ^= x0;
    x0 += k0; x1 += k1 + 3u;
    x0 += x1; x1 = rotl32(x1, 17); x1 ^= x0;
    x0 += x1; x1 = rotl32(x1, 29); x1 ^= x0;
    x0 += x1; x1 = rotl32(x1, 16); x1 ^= x0;
    x0 += x1; x1 = rotl32(x1, 24); x1 ^= x0;
    x0 += k1; x1 += k2 + 4u;
    x0 += x1; x1 = rotl32(x1, 13); x1 ^= x0;
    x0 += x1; x1 = rotl32(x1, 15); x1 ^= x0;
    x0 += x1; x1 = rotl32(x1, 26); x1 ^= x0;
    x0 += x1; x1 = rotl32(x1,  6); x1 ^= x0;
    x0 += k2; x1 += k0 + 5u;
}

// ---------------- 2-phase MFMA GEMM (lda/ldb + optional K-split) ----------
// KSPLIT: blockIdx.z = K-chunk; A/B advance kc*K; Cf advances kc*M*N;
//         bias added only for kc==0.
template <int EPI, bool SPLIT, bool KSPLIT>
__global__ __launch_bounds__(256) void gemm_mfma(
    const uint16_t* __restrict__ Ahi, const uint16_t* __restrict__ Alo,
    const uint16_t* __restrict__ Bhi, const uint16_t* __restrict__ Blo,
    const float* __restrict__ biasp,
    float* __restrict__ Cf, uint16_t* __restrict__ Cb,
    uint16_t* __restrict__ Chi, uint16_t* __restrict__ Clo,
    int M, int N, int K, int lda, int ldb) {
    constexpr int AT = 128 * 32;
    __shared__ __align__(16) uint16_t As[SPLIT ? 2 * AT : AT];
    __shared__ __align__(16) uint16_t Bs[SPLIT ? 2 * AT : AT];

    const int tid = threadIdx.x;
    const int lane = tid & 63, wv = tid >> 6;
    const int wm = wv >> 1, wn = wv & 1;
    const int la = lane & 15, lk = lane >> 4;
    const size_t bm = (size_t)blockIdx.y * 128, bn = (size_t)blockIdx.x * 128;

    int kc = 0;
    if constexpr (KSPLIT) {
        kc = blockIdx.z;
        const size_t ko = (size_t)kc * K;
        Ahi += ko;
        Bhi += ko;
        if constexpr (SPLIT) { Alo += ko; Blo += ko; }
        Cf += (size_t)kc * M * N;
    }

    f32x4 acc[4][4];
#pragma unroll
    for (int i = 0; i < 4; ++i)
#pragma unroll
        for (int j = 0; j < 4; ++j) acc[i][j] = (f32x4){0.f, 0.f, 0.f, 0.f};

    for (int k0 = 0; k0 < K; k0 += 32) {
#pragma unroll
        for (int t = 0; t < 2; ++t) {
            const int cb_ = wv * 128 + t * 64;
            const int c = cb_ + lane;
            const int row = c >> 2, sub = c & 3;
            GLLDS(Ahi + (bm + row) * (size_t)lda + k0 + sub * 8, &As[(size_t)cb_ * 8]);
            GLLDS(Bhi + (bn + row) * (size_t)ldb + k0 + sub * 8, &Bs[(size_t)cb_ * 8]);
            if constexpr (SPLIT) {
                GLLDS(Alo + (bm + row) * (size_t)lda + k0 + sub * 8, &As[AT + (size_t)cb_ * 8]);
                GLLDS(Blo + (bn + row) * (size_t)ldb + k0 + sub * 8, &Bs[AT + (size_t)cb_ * 8]);
            }
        }
        __syncthreads();

        bf16x8 ah[4], bh[4], al[4], bl[4];
#pragma unroll
        for (int i = 0; i < 4; ++i) {
            const int ao = (wm * 64 + i * 16 + la) * 32 + lk * 8;
            const int bo = (wn * 64 + i * 16 + la) * 32 + lk * 8;
            ah[i] = *(const bf16x8*)&As[ao];
            bh[i] = *(const bf16x8*)&Bs[bo];
            if constexpr (SPLIT) {
                al[i] = *(const bf16x8*)&As[AT + ao];
                bl[i] = *(const bf16x8*)&Bs[AT + bo];
            }
        }
#pragma unroll
        for (int i = 0; i < 4; ++i)
#pragma unroll
            for (int j = 0; j < 4; ++j) {
                acc[i][j] = __builtin_amdgcn_mfma_f32_16x16x32_bf16(ah[i], bh[j], acc[i][j], 0, 0, 0);
                if constexpr (SPLIT) {
                    acc[i][j] = __builtin_amdgcn_mfma_f32_16x16x32_bf16(al[i], bh[j], acc[i][j], 0, 0, 0);
                    acc[i][j] = __builtin_amdgcn_mfma_f32_16x16x32_bf16(ah[i], bl[j], acc[i][j], 0, 0, 0);
                }
            }
        __syncthreads();
    }

    const int colb = (int)bn + wn * 64 + la;
    float bj[4];
#pragma unroll
    for (int j = 0; j < 4; ++j) bj[j] = biasp[colb + j * 16];
    if constexpr (KSPLIT) {
        if (kc != 0) {
#pragma unroll
            for (int j = 0; j < 4; ++j) bj[j] = 0.f;
        }
    }
#pragma unroll
    for (int i = 0; i < 4; ++i) {
        const int rb = (int)bm + wm * 64 + i * 16 + lk * 4;
#pragma unroll
        for (int j = 0; j < 4; ++j) {
            const int col = colb + j * 16;
#pragma unroll
            for (int r = 0; r < 4; ++r) {
                float v = acc[i][j][r] + bj[j];
                const size_t idx = (size_t)(rb + r) * N + col;
                if constexpr (EPI == 0) Cf[idx] = v;
                if constexpr (EPI == 1) Cf[idx] = tanhf(v);
                if constexpr (EPI == 2) Cb[idx] = bf16rne(tanhf(v));
                if constexpr (EPI == 3) {
                    float tv = tanhf(v);
                    uint16_t h = bf16rne(tv);
                    Chi[idx] = h;
                    Clo[idx] = bf16rne(tv - b2f(h));
                }
            }
        }
    }
}

// ---------------- weight transpose+convert ----------------
template <bool SPLIT>
__global__ __launch_bounds__(256) void wconv(const float* __restrict__ W,
                                             uint16_t* __restrict__ Thi,
                                             uint16_t* __restrict__ Tlo,
                                             int K, int N) {
    __shared__ float t[32][33];
    const int k0 = blockIdx.x * 32, n0 = blockIdx.y * 32;
    const int tid = threadIdx.x;
    {
        const int kl = tid >> 3, nq = tid & 7;
        float4 v = *(const float4*)(W + (size_t)(k0 + kl) * N + n0 + nq * 4);
        t[kl][nq * 4 + 0] = v.x;
        t[kl][nq * 4 + 1] = v.y;
        t[kl][nq * 4 + 2] = v.z;
        t[kl][nq * 4 + 3] = v.w;
    }
    __syncthreads();
    {
        const int nl = tid >> 3, kq = tid & 7;
        ushort4 hv, lv;
        float f0 = t[kq * 4 + 0][nl], f1 = t[kq * 4 + 1][nl];
        float f2 = t[kq * 4 + 2][nl], f3 = t[kq * 4 + 3][nl];
        hv.x = bf16rne(f0); hv.y = bf16rne(f1); hv.z = bf16rne(f2); hv.w = bf16rne(f3);
        *(ushort4*)(Thi + (size_t)(n0 + nl) * K + k0 + kq * 4) = hv;
        if constexpr (SPLIT) {
            lv.x = bf16rne(f0 - b2f(hv.x)); lv.y = bf16rne(f1 - b2f(hv.y));
            lv.z = bf16rne(f2 - b2f(hv.z)); lv.w = bf16rne(f3 - b2f(hv.w));
            *(ushort4*)(Tlo + (size_t)(n0 + nl) * K + k0 + kq * 4) = lv;
        }
    }
}

// ---------------- x -> hi/lo bf16 split ----------------
__global__ __launch_bounds__(256) void split_x(const float* __restrict__ x,
                                               uint16_t* __restrict__ hi,
                                               uint16_t* __restrict__ lo,
                                               size_t n4) {
    for (size_t i = (size_t)blockIdx.x * 256 + threadIdx.x; i < n4;
         i += (size_t)gridDim.x * 256) {
        float4 v = ((const float4*)x)[i];
        ushort4 h, l;
        h.x = bf16rne(v.x); l.x = bf16rne(v.x - b2f(h.x));
        h.y = bf16rne(v.y); l.y = bf16rne(v.y - b2f(h.y));
        h.z = bf16rne(v.z); l.z = bf16rne(v.z - b2f(h.z));
        h.w = bf16rne(v.w); l.w = bf16rne(v.w - b2f(h.w));
        ((ushort4*)hi)[i] = h;
        ((ushort4*)lo)[i] = l;
    }
}

// ---------------- VQ (NPART>0: h = partials, sum+tanh fused) -------------
template <bool YB16, int NPART>
__global__ __launch_bounds__(256) void vq_kernel(
    const float* __restrict__ h, size_t pstride,
    const float* __restrict__ cb,
    const uint32_t* __restrict__ nlp,
    float* __restrict__ yf, uint16_t* __restrict__ yb,
    uint32_t ka0, uint32_t ka1, uint32_t kb0, uint32_t kb1,
    uint32_t kc0, uint32_t kc1, uint32_t kd0, uint32_t kd1) {
    __shared__ float xs[DCODE];
    __shared__ float sred[NCODE];
    __shared__ int sidx[NCODE];

    const int b = blockIdx.x;
    const int chunk = blockIdx.y;
    const int c = threadIdx.x;

    if (c < DCODE) {
        const size_t idx = (size_t)b * NCODE + chunk * DCODE + c;
        if constexpr (NPART > 0) {
            float z = h[idx];
#pragma unroll
            for (int p = 1; p < NPART; ++p) z += h[(size_t)p * pstride + idx];
            xs[c] = tanhf(z);
        } else {
            xs[c] = h[idx];
        }
    }
    __syncthreads();

    float dot = 0.f, x2 = 0.f, c2 = 0.f;
    const float* crow = cb + c * DCODE;
#pragma unroll 8
    for (int i = 0; i < DCODE; ++i) {
        float xv = xs[i], cv = crow[i];
        dot = fmaf(xv, cv, dot);
        x2 = fmaf(xv, xv, x2);
        c2 = fmaf(cv, cv, c2);
    }
    float d = sqrtf(fmaxf(x2 - 2.f * dot + c2, 0.f));
    float logit = -d * 0.125f;

    sred[c] = logit;
    __syncthreads();
    for (int s = 128; s > 0; s >>= 1) {
        if (c < s) sred[c] = fmaxf(sred[c], sred[c + s]);
        __syncthreads();
    }
    float mx = sred[0];
    __syncthreads();
    float e = expf(logit - mx);
    sred[c] = e;
    __syncthreads();
    for (int s = 128; s > 0; s >>= 1) {
        if (c < s) sred[c] = sred[c] + sred[c + s];
        __syncthreads();
    }
    float ssum = sred[0];
    __syncthreads();
    float r = e / ssum;

    int vi = (int)nlp[0];
    float noise_level = (vi >= -1000000 && vi <= 1000000)
                            ? (float)vi
                            : __uint_as_float(nlp[0]);

    uint32_t lin = (uint32_t)b * 256u + (uint32_t)c;
    uint32_t k0 = chunk == 0 ? ka0 : chunk == 1 ? kb0 : chunk == 2 ? kc0 : kd0;
    uint32_t k1 = chunk == 0 ? ka1 : chunk == 1 ? kb1 : chunk == 2 ? kc1 : kd1;
    uint32_t x0 = 0u, x1 = lin;
    tf2x32(k0, k1, x0, x1);
    uint32_t bits = x0 ^ x1;
    float noise = __uint_as_float((bits >> 9) | 0x3f800000u) - 1.0f;

    float score = r - noise_level * noise;

    sred[c] = score;
    sidx[c] = c;
    __syncthreads();
    for (int s = 128; s > 0; s >>= 1) {
        if (c < s) {
            float ov = sred[c + s];
            int oi = sidx[c + s];
            if (ov > sred[c] || (ov == sred[c] && oi < sidx[c])) {
                sred[c] = ov;
                sidx[c] = oi;
            }
        }
        __syncthreads();
    }
    int best = sidx[0];

    if (c < DCODE) {
        float v = cb[(size_t)best * DCODE + c];
        if constexpr (YB16)
            yb[(size_t)b * NCODE + chunk * DCODE + c] = bf16rne(v);
        else
            yf[(size_t)b * NCODE + chunk * DCODE + c] = v;
    }
}

// ---------------- fallback f32 GEMM (verified Round-4 path) ----------------
template <int BM, int BN, bool TANH>
__global__ __launch_bounds__(256) void gemm_f32(const float* __restrict__ A,
                                                const float* __restrict__ W,
                                                float* __restrict__ C,
                                                int M, int N, int K) {
    constexpr int BK = 16;
    constexpr int TM = BM / 16, TN = BN / 16;
    constexpr int GM = TM / 4, GN = TN / 4;
    constexpr int PA = BM + 4, PB = BN + 4;
    __shared__ float As[BK][PA];
    __shared__ float Bs[BK][PB];

    const int tid = threadIdx.x;
    const int tx = tid & 15, ty = tid >> 4;
    const size_t bm = (size_t)blockIdx.y * BM;
    const size_t bn = (size_t)blockIdx.x * BN;

    float acc[TM][TN];
#pragma unroll
    for (int i = 0; i < TM; ++i)
#pragma unroll
        for (int j = 0; j < TN; ++j) acc[i][j] = 0.f;

    for (int k0 = 0; k0 < K; k0 += BK) {
#pragma unroll
        for (int i = 0; i < BM * BK / 4 / 256; ++i) {
            int f4 = tid + i * 256;
            int row = f4 >> 2;
            int c4 = f4 & 3;
            float4 v = *reinterpret_cast<const float4*>(A + (bm + row) * K + k0 + c4 * 4);
            As[c4 * 4 + 0][row] = v.x;
            As[c4 * 4 + 1][row] = v.y;
            As[c4 * 4 + 2][row] = v.z;
            As[c4 * 4 + 3][row] = v.w;
        }
#pragma unroll
        for (int i = 0; i < BK * BN / 4 / 256; ++i) {
            int f4 = tid + i * 256;
            int row = f4 / (BN / 4);
            int c4 = f4 % (BN / 4);
            *reinterpret_cast<float4*>(&Bs[row][c4 * 4]) =
                *reinterpret_cast<const float4*>(W + (size_t)(k0 + row) * N + bn + c4 * 4);
        }
        __syncthreads();
#pragma unroll
        for (int k = 0; k < BK; ++k) {
            float4 af[GM], bf[GN];
#pragma unroll
            for (int g = 0; g < GM; ++g)
                af[g] = *reinterpret_cast<const float4*>(&As[k][g * 64 + ty * 4]);
#pragma unroll
            for (int g = 0; g < GN; ++g)
                bf[g] = *reinterpret_cast<const float4*>(&Bs[k][g * 64 + tx * 4]);
#pragma unroll
            for (int gm = 0; gm < GM; ++gm) {
                const float* ap = &af[gm].x;
#pragma unroll
                for (int r = 0; r < 4; ++r) {
#pragma unroll
                    for (int gn = 0; gn < GN; ++gn) {
                        const float* bp = &bf[gn].x;
#pragma unroll
                        for (int c = 0; c < 4; ++c)
                            acc[gm * 4 + r][gn * 4 + c] =
                                fmaf(ap[r], bp[c], acc[gm * 4 + r][gn * 4 + c]);
                    }
                }
            }
        }
        __syncthreads();
    }

#pragma unroll
    for (int gm = 0; gm < GM; ++gm) {
#pragma unroll
        for (int r = 0; r < 4; ++r) {
            size_t row = bm + gm * 64 + ty * 4 + r;
#pragma unroll
            for (int gn = 0; gn < GN; ++gn) {
                size_t col = bn + gn * 64 + tx * 4;
                float4 bias = *reinterpret_cast<const float4*>(W + (size_t)K * N + col);
                float4 o;
                o.x = acc[gm * 4 + r][gn * 4 + 0] + bias.x;
                o.y = acc[gm * 4 + r][gn * 4 + 1] + bias.y;
                o.z = acc[gm * 4 + r][gn * 4 + 2] + bias.z;
                o.w = acc[gm * 4 + r][gn * 4 + 3] + bias.w;
                if (TANH) {
                    o.x = tanhf(o.x); o.y = tanhf(o.y);
                    o.z = tanhf(o.z); o.w = tanhf(o.w);
                }
                *reinterpret_cast<float4*>(C + row * N + col) = o;
            }
        }
    }
}

// ---------------- launch ----------------
extern "C" void kernel_launch(void* const* d_in, const int* in_sizes, int n_in,
                              void* d_out, int out_size, void* d_ws, size_t ws_size,
                              hipStream_t stream) {
    const float* x   = (const float*)d_in[0];
    const float* w1e = (const float*)d_in[1];
    const float* w2e = (const float*)d_in[2];
    const float* w1d = (const float*)d_in[3];
    const float* w2d = (const float*)d_in[4];
    const float* cb1 = (const float*)d_in[5];
    const uint32_t* nl = (const uint32_t*)d_in[9];
    float* out = (float*)d_out;

    const int M = in_sizes[0] / IMG_DIM;  // 4096

    uint32_t ks[4][2];
    for (int j = 1; j <= 4; ++j) {
        uint32_t a = 0u, bb = (uint32_t)j;
        tf2x32(0u, 12345u, a, bb);
        ks[j - 1][0] = a;
        ks[j - 1][1] = bb;
    }

    // ws layout (bytes), with time-aliasing:
    const size_t o_h1hi  = 0;           // 134217728  (later: h2 bf16)
    const size_t o_h1lo  = 134217728;   // 134217728
    const size_t o_w1ehi = 268435456;   // 100663296  (later: Wt2d)
    const size_t o_w1elo = 369098752;   // 100663296  (later: Wt1d)
    const size_t o_w2ehi = 469762048;   // 8388608
    const size_t o_w2elo = 478150656;   // 8388608
    const size_t o_h     = 486539264;   // 4194304 (unused in main path)
    const size_t o_y     = 490733568;   // 2097152
    const size_t o_xhi   = 492830720;   // 25165824 (aliased: E2 partials, 16.8MB)
    const size_t o_xlo   = 517996544;   // 25165824
    const size_t NEED    = 543162368;

    uint8_t* ws = (uint8_t*)d_ws;

    if (ws_size >= NEED) {
        uint16_t* h1hi  = (uint16_t*)(ws + o_h1hi);
        uint16_t* h1lo  = (uint16_t*)(ws + o_h1lo);
        uint16_t* w1ehi = (uint16_t*)(ws + o_w1ehi);
        uint16_t* w1elo = (uint16_t*)(ws + o_w1elo);
        uint16_t* w2ehi = (uint16_t*)(ws + o_w2ehi);
        uint16_t* w2elo = (uint16_t*)(ws + o_w2elo);
        uint16_t* ybuf  = (uint16_t*)(ws + o_y);
        uint16_t* xhi   = (uint16_t*)(ws + o_xhi);
        uint16_t* xlo   = (uint16_t*)(ws + o_xlo);
        uint16_t* wt2d  = (uint16_t*)(ws + o_w1ehi);  // alias after E1
        uint16_t* wt1d  = (uint16_t*)(ws + o_w1elo);  // alias after E1
        uint16_t* h2    = (uint16_t*)(ws + o_h1hi);   // alias after E2
        float*    e2p   = (float*)(ws + o_xhi);       // alias after E1

        // prep
        split_x<<<2048, 256, 0, stream>>>(x, xhi, xlo, (size_t)M * IMG_DIM / 4);
        wconv<true><<<dim3(IMG_DIM / 32, HID / 32), 256, 0, stream>>>(w1e, w1ehi, w1elo, IMG_DIM, HID);
        wconv<true><<<dim3(HID / 32, NCODE / 32), 256, 0, stream>>>(w2e, w2ehi, w2elo, HID, NCODE);
        // E1 (2-phase, proven): h1 = tanh(x @ w1e + b) -> bf16 hi/lo
        gemm_mfma<3, true, false><<<dim3(HID / 128, M / 128), 256, 0, stream>>>(
            xhi, xlo, w1ehi, w1elo, w1e + (size_t)IMG_DIM * HID,
            nullptr, nullptr, h1hi, h1lo, M, HID, IMG_DIM, IMG_DIM, IMG_DIM);
        // decoder weight conversions (into regions freed by E1)
        wconv<false><<<dim3(HID / 32, IMG_DIM / 32), 256, 0, stream>>>(w2d, wt2d, nullptr, HID, IMG_DIM);
        wconv<false><<<dim3(NCODE / 32, HID / 32), 256, 0, stream>>>(w1d, wt1d, nullptr, NCODE, HID);
        // E2 split-K x4 (one dispatch, 256 blocks): partials into e2p
        gemm_mfma<0, true, true><<<dim3(NCODE / 128, M / 128, 4), 256, 0, stream>>>(
            h1hi, h1lo, w2ehi, w2elo, w2e + (size_t)HID * NCODE,
            e2p, nullptr, nullptr, nullptr, M, NCODE, HID / 4, HID, HID);
        // VQ (fused partial-sum + tanh) -> y bf16
        vq_kernel<true, 4><<<dim3(M, 4), 256, 0, stream>>>(
            e2p, (size_t)M * NCODE, cb1, nl, nullptr, ybuf,
            ks[0][0], ks[0][1], ks[1][0], ks[1][1],
            ks[2][0], ks[2][1], ks[3][0], ks[3][1]);
        // D1: h2 = tanh(y @ w1d + b) -> bf16
        gemm_mfma<2, false, false><<<dim3(HID / 128, M / 128), 256, 0, stream>>>(
            ybuf, nullptr, wt1d, nullptr, w1d + (size_t)NCODE * HID,
            nullptr, h2, nullptr, nullptr, M, HID, NCODE, NCODE, NCODE);
        // D2: out = h2 @ w2d + b -> f32
        gemm_mfma<0, false, false><<<dim3(IMG_DIM / 128, M / 128), 256, 0, stream>>>(
            h2, nullptr, wt2d, nullptr, w2d + (size_t)HID * IMG_DIM,
            out, nullptr, nullptr, nullptr, M, IMG_DIM, HID, HID, HID);
    } else {
        // fallback: verified f32 path
        float* h1 = (float*)d_ws;
        float* h  = h1 + (size_t)M * HID;
        float* yb = h + (size_t)M * NCODE;
        {
            dim3 g(HID / 128, M / 128);
            gemm_f32<128, 128, true><<<g, 256, 0, stream>>>(x, w1e, h1, M, HID, IMG_DIM);
        }
        {
            dim3 g(NCODE / 64, M / 64);
            gemm_f32<64, 64, true><<<g, 256, 0, stream>>>(h1, w2e, h, M, NCODE, HID);
        }
        vq_kernel<false, 0><<<dim3(M, 4), 256, 0, stream>>>(
            h, 0, cb1, nl, yb, nullptr,
            ks[0][0], ks[0][1], ks[1][0], ks[1][1],
            ks[2][0], ks[2][1], ks[3][0], ks[3][1]);
        {
            dim3 g(HID / 128, M / 128);
            gemm_f32<128, 128, true><<<g, 256, 0, stream>>>(yb, w1d, h1, M, HID, NCODE);
        }
        {
            dim3 g(IMG_DIM / 128, M / 128);
            gemm_f32<128, 128, false><<<g, 256, 0, stream>>>(h1, w2d, out, M, IMG_DIM, HID);
        }
    }
}

// Round 13
// 2510.594 us; speedup vs baseline: 1.6659x; 1.0159x over previous
//
#include <hip/hip_runtime.h>
#include <stdint.h>

// Codec forward. Round 12: attack E1's 8-way LDS bank conflict (1.0e8/dispatch).
// New gemm_ilv for E1: hi/lo interleaved into 128B rows with 8-slot XOR swizzle
// (phys = logical ^ (row&7)); LDS dest stays linear, the per-lane GLOBAL source
// is permuted (rule #21 both-sides) using fixed hi->lo element offsets.
// Same MFMA order -> bitwise-identical numerics to the proven kernel.
// E2 (split-K x4) / D1 / D2 / VQ unchanged.

#define IMG_DIM 3072
#define HID     16384
#define NCODE   256
#define DCODE   64

typedef short bf16x8 __attribute__((ext_vector_type(8)));
typedef float f32x4 __attribute__((ext_vector_type(4)));

__device__ __forceinline__ uint16_t bf16rne(float f) {
    uint32_t u = __float_as_uint(f);
    return (uint16_t)((u + 0x7fffu + ((u >> 16) & 1u)) >> 16);
}
__device__ __forceinline__ float b2f(uint16_t h) {
    return __uint_as_float((uint32_t)h << 16);
}

#define GLLDS(g, l)                                                        \
    __builtin_amdgcn_global_load_lds(                                      \
        (const __attribute__((address_space(1))) uint32_t*)(const void*)(g), \
        (__attribute__((address_space(3))) uint32_t*)(void*)(l), 16, 0, 0)

// ---------------- Threefry2x32 (matches jax/_src/prng.py) ----------------
__host__ __device__ __forceinline__ uint32_t rotl32(uint32_t v, int d) {
    return (v << d) | (v >> (32 - d));
}

__host__ __device__ __forceinline__ void tf2x32(uint32_t k0, uint32_t k1,
                                                uint32_t& x0, uint32_t& x1) {
    uint32_t k2 = k0 ^ k1 ^ 0x1BD11BDAu;
    x0 += k0; x1 += k1;
    x0 += x1; x1 = rotl32(x1, 13); x1 ^= x0;
    x0 += x1; x1 = rotl32(x1, 15); x1 ^= x0;
    x0 += x1; x1 = rotl32(x1, 26); x1 ^= x0;
    x0 += x1; x1 = rotl32(x1,  6); x1 ^= x0;
    x0 += k1; x1 += k2 + 1u;
    x0 += x1; x1 = rotl32(x1, 17); x1 ^= x0;
    x0 += x1; x1 = rotl32(x1, 29); x1 ^= x0;
    x0 += x1; x1 = rotl32(x1, 16); x1 ^= x0;
    x0 += x1; x1 = rotl32(x1, 24); x1 ^= x0;
    x0 += k2; x1 += k0 + 2u;
    x0 += x1; x1 = rotl32(x1, 13); x1 ^= x0;
    x0 += x1; x1 = rotl32(x1, 15); x1 ^= x0;
    x0 += x1; x1 = rotl32(x1, 26); x1 ^= x0;
    x0 += x1; x1 = rotl32(x1,  6); x1 ^= x0;
    x0 += k0; x1 += k1 + 3u;
    x0 += x1; x1 = rotl32(x1, 17); x1 ^= x0;
    x0 += x1; x1 = rotl32(x1, 29); x1 ^= x0;
    x0 += x1; x1 = rotl32(x1, 16); x1 ^= x0;
    x0 += x1; x1 = rotl32(x1, 24); x1 ^= x0;
    x0 += k1; x1 += k2 + 4u;
    x0 += x1; x1 = rotl32(x1, 13); x1 ^= x0;
    x0 += x1; x1 = rotl32(x1, 15); x1 ^= x0;
    x0 += x1; x1 = rotl32(x1, 26); x1 ^= x0;
    x0 += x1; x1 = rotl32(x1,  6); x1 ^= x0;
    x0 += k2; x1 += k0 + 5u;
}

// ------- E1 kernel: SPLIT GEMM, hi/lo-interleaved swizzled LDS (conflict-free)
// LDS row r (128B): phys slot p holds logical slot l = p ^ (r&7);
// logical 0-3 = hi k-sub 0-3, logical 4-7 = lo k-sub 0-3.
// aLo/bLo: element offsets from hi array to lo array (fixed ws layout).
__global__ __launch_bounds__(256) void gemm_ilv(
    const uint16_t* __restrict__ Ahi, size_t aLo,
    const uint16_t* __restrict__ Bhi, size_t bLo,
    const float* __restrict__ biasp,
    uint16_t* __restrict__ Chi, uint16_t* __restrict__ Clo,
    int M, int N, int K, int lda, int ldb) {
    __shared__ __align__(16) uint8_t As[16384];
    __shared__ __align__(16) uint8_t Bs[16384];

    const int tid = threadIdx.x;
    const int lane = tid & 63, wv = tid >> 6;
    const int wm = wv >> 1, wn = wv & 1;
    const int la = lane & 15, lk = lane >> 4;
    const size_t bm = (size_t)blockIdx.y * 128, bn = (size_t)blockIdx.x * 128;

    // per-thread stage source offsets (elements; add k0 per K-step)
    size_t sa[4], sb[4];
    int ldsb[4];
#pragma unroll
    for (int p = 0; p < 4; ++p) {
        const int s = p * 256 + tid;            // 16B slot index in tile
        const int row = s >> 3, pin = s & 7;
        const int logi = pin ^ (row & 7);       // involution
        const int half = logi >> 2, sub = logi & 3;
        sa[p] = (bm + row) * (size_t)lda + sub * 8 + (half ? aLo : 0);
        sb[p] = (bn + row) * (size_t)ldb + sub * 8 + (half ? bLo : 0);
        ldsb[p] = p * 4096 + wv * 1024;         // wave-uniform dest base
    }

    // read: hi phys byte-in-row = (lk ^ (la&7))*16; lo = hi ^ 64
    const int ph = (lk ^ (la & 7)) * 16;

    f32x4 acc[4][4];
#pragma unroll
    for (int i = 0; i < 4; ++i)
#pragma unroll
        for (int j = 0; j < 4; ++j) acc[i][j] = (f32x4){0.f, 0.f, 0.f, 0.f};

    for (int k0 = 0; k0 < K; k0 += 32) {
#pragma unroll
        for (int p = 0; p < 4; ++p) {
            GLLDS(Ahi + sa[p] + k0, As + ldsb[p]);
            GLLDS(Bhi + sb[p] + k0, Bs + ldsb[p]);
        }
        __syncthreads();

        bf16x8 ah[4], bh[4], al[4], bl[4];
#pragma unroll
        for (int i = 0; i < 4; ++i) {
            const int ra = (wm * 64 + i * 16 + la) * 128;
            const int rb = (wn * 64 + i * 16 + la) * 128;
            ah[i] = *(const bf16x8*)(As + ra + ph);
            al[i] = *(const bf16x8*)(As + ra + (ph ^ 64));
            bh[i] = *(const bf16x8*)(Bs + rb + ph);
            bl[i] = *(const bf16x8*)(Bs + rb + (ph ^ 64));
        }
#pragma unroll
        for (int i = 0; i < 4; ++i)
#pragma unroll
            for (int j = 0; j < 4; ++j) {
                acc[i][j] = __builtin_amdgcn_mfma_f32_16x16x32_bf16(ah[i], bh[j], acc[i][j], 0, 0, 0);
                acc[i][j] = __builtin_amdgcn_mfma_f32_16x16x32_bf16(al[i], bh[j], acc[i][j], 0, 0, 0);
                acc[i][j] = __builtin_amdgcn_mfma_f32_16x16x32_bf16(ah[i], bl[j], acc[i][j], 0, 0, 0);
            }
        __syncthreads();
    }

    // epilogue (EPI==3 behavior: bf16 hi/lo tanh)
    const int colb = (int)bn + wn * 64 + la;
    float bj[4];
#pragma unroll
    for (int j = 0; j < 4; ++j) bj[j] = biasp[colb + j * 16];
#pragma unroll
    for (int i = 0; i < 4; ++i) {
        const int rb = (int)bm + wm * 64 + i * 16 + lk * 4;
#pragma unroll
        for (int j = 0; j < 4; ++j) {
            const int col = colb + j * 16;
#pragma unroll
            for (int r = 0; r < 4; ++r) {
                float v = acc[i][j][r] + bj[j];
                const size_t idx = (size_t)(rb + r) * N + col;
                float tv = tanhf(v);
                uint16_t h = bf16rne(tv);
                Chi[idx] = h;
                Clo[idx] = bf16rne(tv - b2f(h));
            }
        }
    }
}

// ---------------- 2-phase MFMA GEMM (lda/ldb + optional K-split) ----------
template <int EPI, bool SPLIT, bool KSPLIT>
__global__ __launch_bounds__(256) void gemm_mfma(
    const uint16_t* __restrict__ Ahi, const uint16_t* __restrict__ Alo,
    const uint16_t* __restrict__ Bhi, const uint16_t* __restrict__ Blo,
    const float* __restrict__ biasp,
    float* __restrict__ Cf, uint16_t* __restrict__ Cb,
    uint16_t* __restrict__ Chi, uint16_t* __restrict__ Clo,
    int M, int N, int K, int lda, int ldb) {
    constexpr int AT = 128 * 32;
    __shared__ __align__(16) uint16_t As[SPLIT ? 2 * AT : AT];
    __shared__ __align__(16) uint16_t Bs[SPLIT ? 2 * AT : AT];

    const int tid = threadIdx.x;
    const int lane = tid & 63, wv = tid >> 6;
    const int wm = wv >> 1, wn = wv & 1;
    const int la = lane & 15, lk = lane >> 4;
    const size_t bm = (size_t)blockIdx.y * 128, bn = (size_t)blockIdx.x * 128;

    int kc = 0;
    if constexpr (KSPLIT) {
        kc = blockIdx.z;
        const size_t ko = (size_t)kc * K;
        Ahi += ko;
        Bhi += ko;
        if constexpr (SPLIT) { Alo += ko; Blo += ko; }
        Cf += (size_t)kc * M * N;
    }

    f32x4 acc[4][4];
#pragma unroll
    for (int i = 0; i < 4; ++i)
#pragma unroll
        for (int j = 0; j < 4; ++j) acc[i][j] = (f32x4){0.f, 0.f, 0.f, 0.f};

    for (int k0 = 0; k0 < K; k0 += 32) {
#pragma unroll
        for (int t = 0; t < 2; ++t) {
            const int cb_ = wv * 128 + t * 64;
            const int c = cb_ + lane;
            const int row = c >> 2, sub = c & 3;
            GLLDS(Ahi + (bm + row) * (size_t)lda + k0 + sub * 8, &As[(size_t)cb_ * 8]);
            GLLDS(Bhi + (bn + row) * (size_t)ldb + k0 + sub * 8, &Bs[(size_t)cb_ * 8]);
            if constexpr (SPLIT) {
                GLLDS(Alo + (bm + row) * (size_t)lda + k0 + sub * 8, &As[AT + (size_t)cb_ * 8]);
                GLLDS(Blo + (bn + row) * (size_t)ldb + k0 + sub * 8, &Bs[AT + (size_t)cb_ * 8]);
            }
        }
        __syncthreads();

        bf16x8 ah[4], bh[4], al[4], bl[4];
#pragma unroll
        for (int i = 0; i < 4; ++i) {
            const int ao = (wm * 64 + i * 16 + la) * 32 + lk * 8;
            const int bo = (wn * 64 + i * 16 + la) * 32 + lk * 8;
            ah[i] = *(const bf16x8*)&As[ao];
            bh[i] = *(const bf16x8*)&Bs[bo];
            if constexpr (SPLIT) {
                al[i] = *(const bf16x8*)&As[AT + ao];
                bl[i] = *(const bf16x8*)&Bs[AT + bo];
            }
        }
#pragma unroll
        for (int i = 0; i < 4; ++i)
#pragma unroll
            for (int j = 0; j < 4; ++j) {
                acc[i][j] = __builtin_amdgcn_mfma_f32_16x16x32_bf16(ah[i], bh[j], acc[i][j], 0, 0, 0);
                if constexpr (SPLIT) {
                    acc[i][j] = __builtin_amdgcn_mfma_f32_16x16x32_bf16(al[i], bh[j], acc[i][j], 0, 0, 0);
                    acc[i][j] = __builtin_amdgcn_mfma_f32_16x16x32_bf16(ah[i], bl[j], acc[i][j], 0, 0, 0);
                }
            }
        __syncthreads();
    }

    const int colb = (int)bn + wn * 64 + la;
    float bj[4];
#pragma unroll
    for (int j = 0; j < 4; ++j) bj[j] = biasp[colb + j * 16];
    if constexpr (KSPLIT) {
        if (kc != 0) {
#pragma unroll
            for (int j = 0; j < 4; ++j) bj[j] = 0.f;
        }
    }
#pragma unroll
    for (int i = 0; i < 4; ++i) {
        const int rb = (int)bm + wm * 64 + i * 16 + lk * 4;
#pragma unroll
        for (int j = 0; j < 4; ++j) {
            const int col = colb + j * 16;
#pragma unroll
            for (int r = 0; r < 4; ++r) {
                float v = acc[i][j][r] + bj[j];
                const size_t idx = (size_t)(rb + r) * N + col;
                if constexpr (EPI == 0) Cf[idx] = v;
                if constexpr (EPI == 1) Cf[idx] = tanhf(v);
                if constexpr (EPI == 2) Cb[idx] = bf16rne(tanhf(v));
                if constexpr (EPI == 3) {
                    float tv = tanhf(v);
                    uint16_t h = bf16rne(tv);
                    Chi[idx] = h;
                    Clo[idx] = bf16rne(tv - b2f(h));
                }
            }
        }
    }
}

// ---------------- weight transpose+convert ----------------
template <bool SPLIT>
__global__ __launch_bounds__(256) void wconv(const float* __restrict__ W,
                                             uint16_t* __restrict__ Thi,
                                             uint16_t* __restrict__ Tlo,
                                             int K, int N) {
    __shared__ float t[32][33];
    const int k0 = blockIdx.x * 32, n0 = blockIdx.y * 32;
    const int tid = threadIdx.x;
    {
        const int kl = tid >> 3, nq = tid & 7;
        float4 v = *(const float4*)(W + (size_t)(k0 + kl) * N + n0 + nq * 4);
        t[kl][nq * 4 + 0] = v.x;
        t[kl][nq * 4 + 1] = v.y;
        t[kl][nq * 4 + 2] = v.z;
        t[kl][nq * 4 + 3] = v.w;
    }
    __syncthreads();
    {
        const int nl = tid >> 3, kq = tid & 7;
        ushort4 hv, lv;
        float f0 = t[kq * 4 + 0][nl], f1 = t[kq * 4 + 1][nl];
        float f2 = t[kq * 4 + 2][nl], f3 = t[kq * 4 + 3][nl];
        hv.x = bf16rne(f0); hv.y = bf16rne(f1); hv.z = bf16rne(f2); hv.w = bf16rne(f3);
        *(ushort4*)(Thi + (size_t)(n0 + nl) * K + k0 + kq * 4) = hv;
        if constexpr (SPLIT) {
            lv.x = bf16rne(f0 - b2f(hv.x)); lv.y = bf16rne(f1 - b2f(hv.y));
            lv.z = bf16rne(f2 - b2f(hv.z)); lv.w = bf16rne(f3 - b2f(hv.w));
            *(ushort4*)(Tlo + (size_t)(n0 + nl) * K + k0 + kq * 4) = lv;
        }
    }
}

// ---------------- x -> hi/lo bf16 split ----------------
__global__ __launch_bounds__(256) void split_x(const float* __restrict__ x,
                                               uint16_t* __restrict__ hi,
                                               uint16_t* __restrict__ lo,
                                               size_t n4) {
    for (size_t i = (size_t)blockIdx.x * 256 + threadIdx.x; i < n4;
         i += (size_t)gridDim.x * 256) {
        float4 v = ((const float4*)x)[i];
        ushort4 h, l;
        h.x = bf16rne(v.x); l.x = bf16rne(v.x - b2f(h.x));
        h.y = bf16rne(v.y); l.y = bf16rne(v.y - b2f(h.y));
        h.z = bf16rne(v.z); l.z = bf16rne(v.z - b2f(h.z));
        h.w = bf16rne(v.w); l.w = bf16rne(v.w - b2f(h.w));
        ((ushort4*)hi)[i] = h;
        ((ushort4*)lo)[i] = l;
    }
}

// ---------------- VQ (NPART>0: h = partials, sum+tanh fused) -------------
template <bool YB16, int NPART>
__global__ __launch_bounds__(256) void vq_kernel(
    const float* __restrict__ h, size_t pstride,
    const float* __restrict__ cb,
    const uint32_t* __restrict__ nlp,
    float* __restrict__ yf, uint16_t* __restrict__ yb,
    uint32_t ka0, uint32_t ka1, uint32_t kb0, uint32_t kb1,
    uint32_t kc0, uint32_t kc1, uint32_t kd0, uint32_t kd1) {
    __shared__ float xs[DCODE];
    __shared__ float sred[NCODE];
    __shared__ int sidx[NCODE];

    const int b = blockIdx.x;
    const int chunk = blockIdx.y;
    const int c = threadIdx.x;

    if (c < DCODE) {
        const size_t idx = (size_t)b * NCODE + chunk * DCODE + c;
        if constexpr (NPART > 0) {
            float z = h[idx];
#pragma unroll
            for (int p = 1; p < NPART; ++p) z += h[(size_t)p * pstride + idx];
            xs[c] = tanhf(z);
        } else {
            xs[c] = h[idx];
        }
    }
    __syncthreads();

    float dot = 0.f, x2 = 0.f, c2 = 0.f;
    const float* crow = cb + c * DCODE;
#pragma unroll 8
    for (int i = 0; i < DCODE; ++i) {
        float xv = xs[i], cv = crow[i];
        dot = fmaf(xv, cv, dot);
        x2 = fmaf(xv, xv, x2);
        c2 = fmaf(cv, cv, c2);
    }
    float d = sqrtf(fmaxf(x2 - 2.f * dot + c2, 0.f));
    float logit = -d * 0.125f;

    sred[c] = logit;
    __syncthreads();
    for (int s = 128; s > 0; s >>= 1) {
        if (c < s) sred[c] = fmaxf(sred[c], sred[c + s]);
        __syncthreads();
    }
    float mx = sred[0];
    __syncthreads();
    float e = expf(logit - mx);
    sred[c] = e;
    __syncthreads();
    for (int s = 128; s > 0; s >>= 1) {
        if (c < s) sred[c] = sred[c] + sred[c + s];
        __syncthreads();
    }
    float ssum = sred[0];
    __syncthreads();
    float r = e / ssum;

    int vi = (int)nlp[0];
    float noise_level = (vi >= -1000000 && vi <= 1000000)
                            ? (float)vi
                            : __uint_as_float(nlp[0]);

    uint32_t lin = (uint32_t)b * 256u + (uint32_t)c;
    uint32_t k0 = chunk == 0 ? ka0 : chunk == 1 ? kb0 : chunk == 2 ? kc0 : kd0;
    uint32_t k1 = chunk == 0 ? ka1 : chunk == 1 ? kb1 : chunk == 2 ? kc1 : kd1;
    uint32_t x0 = 0u, x1 = lin;
    tf2x32(k0, k1, x0, x1);
    uint32_t bits = x0 ^ x1;
    float noise = __uint_as_float((bits >> 9) | 0x3f800000u) - 1.0f;

    float score = r - noise_level * noise;

    sred[c] = score;
    sidx[c] = c;
    __syncthreads();
    for (int s = 128; s > 0; s >>= 1) {
        if (c < s) {
            float ov = sred[c + s];
            int oi = sidx[c + s];
            if (ov > sred[c] || (ov == sred[c] && oi < sidx[c])) {
                sred[c] = ov;
                sidx[c] = oi;
            }
        }
        __syncthreads();
    }
    int best = sidx[0];

    if (c < DCODE) {
        float v = cb[(size_t)best * DCODE + c];
        if constexpr (YB16)
            yb[(size_t)b * NCODE + chunk * DCODE + c] = bf16rne(v);
        else
            yf[(size_t)b * NCODE + chunk * DCODE + c] = v;
    }
}

// ---------------- fallback f32 GEMM (verified Round-4 path) ----------------
template <int BM, int BN, bool TANH>
__global__ __launch_bounds__(256) void gemm_f32(const float* __restrict__ A,
                                                const float* __restrict__ W,
                                                float* __restrict__ C,
                                                int M, int N, int K) {
    constexpr int BK = 16;
    constexpr int TM = BM / 16, TN = BN / 16;
    constexpr int GM = TM / 4, GN = TN / 4;
    constexpr int PA = BM + 4, PB = BN + 4;
    __shared__ float As[BK][PA];
    __shared__ float Bs[BK][PB];

    const int tid = threadIdx.x;
    const int tx = tid & 15, ty = tid >> 4;
    const size_t bm = (size_t)blockIdx.y * BM;
    const size_t bn = (size_t)blockIdx.x * BN;

    float acc[TM][TN];
#pragma unroll
    for (int i = 0; i < TM; ++i)
#pragma unroll
        for (int j = 0; j < TN; ++j) acc[i][j] = 0.f;

    for (int k0 = 0; k0 < K; k0 += BK) {
#pragma unroll
        for (int i = 0; i < BM * BK / 4 / 256; ++i) {
            int f4 = tid + i * 256;
            int row = f4 >> 2;
            int c4 = f4 & 3;
            float4 v = *reinterpret_cast<const float4*>(A + (bm + row) * K + k0 + c4 * 4);
            As[c4 * 4 + 0][row] = v.x;
            As[c4 * 4 + 1][row] = v.y;
            As[c4 * 4 + 2][row] = v.z;
            As[c4 * 4 + 3][row] = v.w;
        }
#pragma unroll
        for (int i = 0; i < BK * BN / 4 / 256; ++i) {
            int f4 = tid + i * 256;
            int row = f4 / (BN / 4);
            int c4 = f4 % (BN / 4);
            *reinterpret_cast<float4*>(&Bs[row][c4 * 4]) =
                *reinterpret_cast<const float4*>(W + (size_t)(k0 + row) * N + bn + c4 * 4);
        }
        __syncthreads();
#pragma unroll
        for (int k = 0; k < BK; ++k) {
            float4 af[GM], bf[GN];
#pragma unroll
            for (int g = 0; g < GM; ++g)
                af[g] = *reinterpret_cast<const float4*>(&As[k][g * 64 + ty * 4]);
#pragma unroll
            for (int g = 0; g < GN; ++g)
                bf[g] = *reinterpret_cast<const float4*>(&Bs[k][g * 64 + tx * 4]);
#pragma unroll
            for (int gm = 0; gm < GM; ++gm) {
                const float* ap = &af[gm].x;
#pragma unroll
                for (int r = 0; r < 4; ++r) {
#pragma unroll
                    for (int gn = 0; gn < GN; ++gn) {
                        const float* bp = &bf[gn].x;
#pragma unroll
                        for (int c = 0; c < 4; ++c)
                            acc[gm * 4 + r][gn * 4 + c] =
                                fmaf(ap[r], bp[c], acc[gm * 4 + r][gn * 4 + c]);
                    }
                }
            }
        }
        __syncthreads();
    }

#pragma unroll
    for (int gm = 0; gm < GM; ++gm) {
#pragma unroll
        for (int r = 0; r < 4; ++r) {
            size_t row = bm + gm * 64 + ty * 4 + r;
#pragma unroll
            for (int gn = 0; gn < GN; ++gn) {
                size_t col = bn + gn * 64 + tx * 4;
                float4 bias = *reinterpret_cast<const float4*>(W + (size_t)K * N + col);
                float4 o;
                o.x = acc[gm * 4 + r][gn * 4 + 0] + bias.x;
                o.y = acc[gm * 4 + r][gn * 4 + 1] + bias.y;
                o.z = acc[gm * 4 + r][gn * 4 + 2] + bias.z;
                o.w = acc[gm * 4 + r][gn * 4 + 3] + bias.w;
                if (TANH) {
                    o.x = tanhf(o.x); o.y = tanhf(o.y);
                    o.z = tanhf(o.z); o.w = tanhf(o.w);
                }
                *reinterpret_cast<float4*>(C + row * N + col) = o;
            }
        }
    }
}

// ---------------- launch ----------------
extern "C" void kernel_launch(void* const* d_in, const int* in_sizes, int n_in,
                              void* d_out, int out_size, void* d_ws, size_t ws_size,
                              hipStream_t stream) {
    const float* x   = (const float*)d_in[0];
    const float* w1e = (const float*)d_in[1];
    const float* w2e = (const float*)d_in[2];
    const float* w1d = (const float*)d_in[3];
    const float* w2d = (const float*)d_in[4];
    const float* cb1 = (const float*)d_in[5];
    const uint32_t* nl = (const uint32_t*)d_in[9];
    float* out = (float*)d_out;

    const int M = in_sizes[0] / IMG_DIM;  // 4096

    uint32_t ks[4][2];
    for (int j = 1; j <= 4; ++j) {
        uint32_t a = 0u, bb = (uint32_t)j;
        tf2x32(0u, 12345u, a, bb);
        ks[j - 1][0] = a;
        ks[j - 1][1] = bb;
    }

    // ws layout (bytes), with time-aliasing:
    const size_t o_h1hi  = 0;           // 134217728  (later: h2 bf16)
    const size_t o_h1lo  = 134217728;   // 134217728
    const size_t o_w1ehi = 268435456;   // 100663296  (later: Wt2d)
    const size_t o_w1elo = 369098752;   // 100663296  (later: Wt1d)
    const size_t o_w2ehi = 469762048;   // 8388608
    const size_t o_w2elo = 478150656;   // 8388608
    const size_t o_h     = 486539264;   // 4194304 (unused in main path)
    const size_t o_y     = 490733568;   // 2097152
    const size_t o_xhi   = 492830720;   // 25165824 (aliased: E2 partials, 16.8MB)
    const size_t o_xlo   = 517996544;   // 25165824
    const size_t NEED    = 543162368;

    uint8_t* ws = (uint8_t*)d_ws;

    if (ws_size >= NEED) {
        uint16_t* h1hi  = (uint16_t*)(ws + o_h1hi);
        uint16_t* h1lo  = (uint16_t*)(ws + o_h1lo);
        uint16_t* w1ehi = (uint16_t*)(ws + o_w1ehi);
        uint16_t* w1elo = (uint16_t*)(ws + o_w1elo);
        uint16_t* w2ehi = (uint16_t*)(ws + o_w2ehi);
        uint16_t* w2elo = (uint16_t*)(ws + o_w2elo);
        uint16_t* ybuf  = (uint16_t*)(ws + o_y);
        uint16_t* xhi   = (uint16_t*)(ws + o_xhi);
        uint16_t* xlo   = (uint16_t*)(ws + o_xlo);
        uint16_t* wt2d  = (uint16_t*)(ws + o_w1ehi);  // alias after E1
        uint16_t* wt1d  = (uint16_t*)(ws + o_w1elo);  // alias after E1
        uint16_t* h2    = (uint16_t*)(ws + o_h1hi);   // alias after E2
        float*    e2p   = (float*)(ws + o_xhi);       // alias after E1

        // hi->lo element offsets (fixed by layout above)
        const size_t aLo = (o_xlo - o_xhi) / 2;       // 12582912
        const size_t bLo = (o_w1elo - o_w1ehi) / 2;   // 50331648

        // prep
        split_x<<<2048, 256, 0, stream>>>(x, xhi, xlo, (size_t)M * IMG_DIM / 4);
        wconv<true><<<dim3(IMG_DIM / 32, HID / 32), 256, 0, stream>>>(w1e, w1ehi, w1elo, IMG_DIM, HID);
        wconv<true><<<dim3(HID / 32, NCODE / 32), 256, 0, stream>>>(w2e, w2ehi, w2elo, HID, NCODE);
        // E1 (interleaved-swizzled): h1 = tanh(x @ w1e + b) -> bf16 hi/lo
        gemm_ilv<<<dim3(HID / 128, M / 128), 256, 0, stream>>>(
            xhi, aLo, w1ehi, bLo, w1e + (size_t)IMG_DIM * HID,
            h1hi, h1lo, M, HID, IMG_DIM, IMG_DIM, IMG_DIM);
        // decoder weight conversions (into regions freed by E1)
        wconv<false><<<dim3(HID / 32, IMG_DIM / 32), 256, 0, stream>>>(w2d, wt2d, nullptr, HID, IMG_DIM);
        wconv<false><<<dim3(NCODE / 32, HID / 32), 256, 0, stream>>>(w1d, wt1d, nullptr, NCODE, HID);
        // E2 split-K x4 (one dispatch, 256 blocks): partials into e2p
        gemm_mfma<0, true, true><<<dim3(NCODE / 128, M / 128, 4), 256, 0, stream>>>(
            h1hi, h1lo, w2ehi, w2elo, w2e + (size_t)HID * NCODE,
            e2p, nullptr, nullptr, nullptr, M, NCODE, HID / 4, HID, HID);
        // VQ (fused partial-sum + tanh) -> y bf16
        vq_kernel<true, 4><<<dim3(M, 4), 256, 0, stream>>>(
            e2p, (size_t)M * NCODE, cb1, nl, nullptr, ybuf,
            ks[0][0], ks[0][1], ks[1][0], ks[1][1],
            ks[2][0], ks[2][1], ks[3][0], ks[3][1]);
        // D1: h2 = tanh(y @ w1d + b) -> bf16
        gemm_mfma<2, false, false><<<dim3(HID / 128, M / 128), 256, 0, stream>>>(
            ybuf, nullptr, wt1d, nullptr, w1d + (size_t)NCODE * HID,
            nullptr, h2, nullptr, nullptr, M, HID, NCODE, NCODE, NCODE);
        // D2: out = h2 @ w2d + b -> f32
        gemm_mfma<0, false, false><<<dim3(IMG_DIM / 128, M / 128), 256, 0, stream>>>(
            h2, nullptr, wt2d, nullptr, w2d + (size_t)HID * IMG_DIM,
            out, nullptr, nullptr, nullptr, M, IMG_DIM, HID, HID, HID);
    } else {
        // fallback: verified f32 path
        float* h1 = (float*)d_ws;
        float* h  = h1 + (size_t)M * HID;
        float* yb = h + (size_t)M * NCODE;
        {
            dim3 g(HID / 128, M / 128);
            gemm_f32<128, 128, true><<<g, 256, 0, stream>>>(x, w1e, h1, M, HID, IMG_DIM);
        }
        {
            dim3 g(NCODE / 64, M / 64);
            gemm_f32<64, 64, true><<<g, 256, 0, stream>>>(h1, w2e, h, M, NCODE, HID);
        }
        vq_kernel<false, 0><<<dim3(M, 4), 256, 0, stream>>>(
            h, 0, cb1, nl, yb, nullptr,
            ks[0][0], ks[0][1], ks[1][0], ks[1][1],
            ks[2][0], ks[2][1], ks[3][0], ks[3][1]);
        {
            dim3 g(HID / 128, M / 128);
            gemm_f32<128, 128, true><<<g, 256, 0, stream>>>(yb, w1d, h1, M, HID, NCODE);
        }
        {
            dim3 g(IMG_DIM / 128, M / 128);
            gemm_f32<128, 128, false><<<g, 256, 0, stream>>>(h1, w2d, out, M, IMG_DIM, HID);
        }
    }
}

// Round 14
// 2493.294 us; speedup vs baseline: 1.6775x; 1.0069x over previous
//
#include <hip/hip_runtime.h>
#include <stdint.h>

// Codec forward. Round 13: wconv2 — coalesced 64x64 weight transpose
// (32B/lane contiguous writes along K, padded LDS). ~3x faster than the
// old 32x32 wconv; outputs bitwise-identical. All GEMMs unchanged:
//   E1: gemm_ilv (conflict-free swizzled, 890 TF = 2-phase ceiling)
//   E2: split-K x4 + fused partial-sum VQ; D1/D2: plain bf16 2-phase.

#define IMG_DIM 3072
#define HID     16384
#define NCODE   256
#define DCODE   64

typedef short bf16x8 __attribute__((ext_vector_type(8)));
typedef float f32x4 __attribute__((ext_vector_type(4)));

__device__ __forceinline__ uint16_t bf16rne(float f) {
    uint32_t u = __float_as_uint(f);
    return (uint16_t)((u + 0x7fffu + ((u >> 16) & 1u)) >> 16);
}
__device__ __forceinline__ float b2f(uint16_t h) {
    return __uint_as_float((uint32_t)h << 16);
}

#define GLLDS(g, l)                                                        \
    __builtin_amdgcn_global_load_lds(                                      \
        (const __attribute__((address_space(1))) uint32_t*)(const void*)(g), \
        (__attribute__((address_space(3))) uint32_t*)(void*)(l), 16, 0, 0)

// ---------------- Threefry2x32 (matches jax/_src/prng.py) ----------------
__host__ __device__ __forceinline__ uint32_t rotl32(uint32_t v, int d) {
    return (v << d) | (v >> (32 - d));
}

__host__ __device__ __forceinline__ void tf2x32(uint32_t k0, uint32_t k1,
                                                uint32_t& x0, uint32_t& x1) {
    uint32_t k2 = k0 ^ k1 ^ 0x1BD11BDAu;
    x0 += k0; x1 += k1;
    x0 += x1; x1 = rotl32(x1, 13); x1 ^= x0;
    x0 += x1; x1 = rotl32(x1, 15); x1 ^= x0;
    x0 += x1; x1 = rotl32(x1, 26); x1 ^= x0;
    x0 += x1; x1 = rotl32(x1,  6); x1 ^= x0;
    x0 += k1; x1 += k2 + 1u;
    x0 += x1; x1 = rotl32(x1, 17); x1 ^= x0;
    x0 += x1; x1 = rotl32(x1, 29); x1 ^= x0;
    x0 += x1; x1 = rotl32(x1, 16); x1 ^= x0;
    x0 += x1; x1 = rotl32(x1, 24); x1 ^= x0;
    x0 += k2; x1 += k0 + 2u;
    x0 += x1; x1 = rotl32(x1, 13); x1 ^= x0;
    x0 += x1; x1 = rotl32(x1, 15); x1 ^= x0;
    x0 += x1; x1 = rotl32(x1, 26); x1 ^= x0;
    x0 += x1; x1 = rotl32(x1,  6); x1 ^= x0;
    x0 += k0; x1 += k1 + 3u;
    x0 += x1; x1 = rotl32(x1, 17); x1 ^= x0;
    x0 += x1; x1 = rotl32(x1, 29); x1 ^= x0;
    x0 += x1; x1 = rotl32(x1, 16); x1 ^= x0;
    x0 += x1; x1 = rotl32(x1, 24); x1 ^= x0;
    x0 += k1; x1 += k2 + 4u;
    x0 += x1; x1 = rotl32(x1, 13); x1 ^= x0;
    x0 += x1; x1 = rotl32(x1, 15); x1 ^= x0;
    x0 += x1; x1 = rotl32(x1, 26); x1 ^= x0;
    x0 += x1; x1 = rotl32(x1,  6); x1 ^= x0;
    x0 += k2; x1 += k0 + 5u;
}

// ------- E1 kernel: SPLIT GEMM, hi/lo-interleaved swizzled LDS (conflict-free)
__global__ __launch_bounds__(256) void gemm_ilv(
    const uint16_t* __restrict__ Ahi, size_t aLo,
    const uint16_t* __restrict__ Bhi, size_t bLo,
    const float* __restrict__ biasp,
    uint16_t* __restrict__ Chi, uint16_t* __restrict__ Clo,
    int M, int N, int K, int lda, int ldb) {
    __shared__ __align__(16) uint8_t As[16384];
    __shared__ __align__(16) uint8_t Bs[16384];

    const int tid = threadIdx.x;
    const int lane = tid & 63, wv = tid >> 6;
    const int wm = wv >> 1, wn = wv & 1;
    const int la = lane & 15, lk = lane >> 4;
    const size_t bm = (size_t)blockIdx.y * 128, bn = (size_t)blockIdx.x * 128;

    size_t sa[4], sb[4];
    int ldsb[4];
#pragma unroll
    for (int p = 0; p < 4; ++p) {
        const int s = p * 256 + tid;
        const int row = s >> 3, pin = s & 7;
        const int logi = pin ^ (row & 7);
        const int half = logi >> 2, sub = logi & 3;
        sa[p] = (bm + row) * (size_t)lda + sub * 8 + (half ? aLo : 0);
        sb[p] = (bn + row) * (size_t)ldb + sub * 8 + (half ? bLo : 0);
        ldsb[p] = p * 4096 + wv * 1024;
    }

    const int ph = (lk ^ (la & 7)) * 16;

    f32x4 acc[4][4];
#pragma unroll
    for (int i = 0; i < 4; ++i)
#pragma unroll
        for (int j = 0; j < 4; ++j) acc[i][j] = (f32x4){0.f, 0.f, 0.f, 0.f};

    for (int k0 = 0; k0 < K; k0 += 32) {
#pragma unroll
        for (int p = 0; p < 4; ++p) {
            GLLDS(Ahi + sa[p] + k0, As + ldsb[p]);
            GLLDS(Bhi + sb[p] + k0, Bs + ldsb[p]);
        }
        __syncthreads();

        bf16x8 ah[4], bh[4], al[4], bl[4];
#pragma unroll
        for (int i = 0; i < 4; ++i) {
            const int ra = (wm * 64 + i * 16 + la) * 128;
            const int rb = (wn * 64 + i * 16 + la) * 128;
            ah[i] = *(const bf16x8*)(As + ra + ph);
            al[i] = *(const bf16x8*)(As + ra + (ph ^ 64));
            bh[i] = *(const bf16x8*)(Bs + rb + ph);
            bl[i] = *(const bf16x8*)(Bs + rb + (ph ^ 64));
        }
#pragma unroll
        for (int i = 0; i < 4; ++i)
#pragma unroll
            for (int j = 0; j < 4; ++j) {
                acc[i][j] = __builtin_amdgcn_mfma_f32_16x16x32_bf16(ah[i], bh[j], acc[i][j], 0, 0, 0);
                acc[i][j] = __builtin_amdgcn_mfma_f32_16x16x32_bf16(al[i], bh[j], acc[i][j], 0, 0, 0);
                acc[i][j] = __builtin_amdgcn_mfma_f32_16x16x32_bf16(ah[i], bl[j], acc[i][j], 0, 0, 0);
            }
        __syncthreads();
    }

    const int colb = (int)bn + wn * 64 + la;
    float bj[4];
#pragma unroll
    for (int j = 0; j < 4; ++j) bj[j] = biasp[colb + j * 16];
#pragma unroll
    for (int i = 0; i < 4; ++i) {
        const int rb = (int)bm + wm * 64 + i * 16 + lk * 4;
#pragma unroll
        for (int j = 0; j < 4; ++j) {
            const int col = colb + j * 16;
#pragma unroll
            for (int r = 0; r < 4; ++r) {
                float v = acc[i][j][r] + bj[j];
                const size_t idx = (size_t)(rb + r) * N + col;
                float tv = tanhf(v);
                uint16_t h = bf16rne(tv);
                Chi[idx] = h;
                Clo[idx] = bf16rne(tv - b2f(h));
            }
        }
    }
}

// ---------------- 2-phase MFMA GEMM (lda/ldb + optional K-split) ----------
template <int EPI, bool SPLIT, bool KSPLIT>
__global__ __launch_bounds__(256) void gemm_mfma(
    const uint16_t* __restrict__ Ahi, const uint16_t* __restrict__ Alo,
    const uint16_t* __restrict__ Bhi, const uint16_t* __restrict__ Blo,
    const float* __restrict__ biasp,
    float* __restrict__ Cf, uint16_t* __restrict__ Cb,
    uint16_t* __restrict__ Chi, uint16_t* __restrict__ Clo,
    int M, int N, int K, int lda, int ldb) {
    constexpr int AT = 128 * 32;
    __shared__ __align__(16) uint16_t As[SPLIT ? 2 * AT : AT];
    __shared__ __align__(16) uint16_t Bs[SPLIT ? 2 * AT : AT];

    const int tid = threadIdx.x;
    const int lane = tid & 63, wv = tid >> 6;
    const int wm = wv >> 1, wn = wv & 1;
    const int la = lane & 15, lk = lane >> 4;
    const size_t bm = (size_t)blockIdx.y * 128, bn = (size_t)blockIdx.x * 128;

    int kc = 0;
    if constexpr (KSPLIT) {
        kc = blockIdx.z;
        const size_t ko = (size_t)kc * K;
        Ahi += ko;
        Bhi += ko;
        if constexpr (SPLIT) { Alo += ko; Blo += ko; }
        Cf += (size_t)kc * M * N;
    }

    f32x4 acc[4][4];
#pragma unroll
    for (int i = 0; i < 4; ++i)
#pragma unroll
        for (int j = 0; j < 4; ++j) acc[i][j] = (f32x4){0.f, 0.f, 0.f, 0.f};

    for (int k0 = 0; k0 < K; k0 += 32) {
#pragma unroll
        for (int t = 0; t < 2; ++t) {
            const int cb_ = wv * 128 + t * 64;
            const int c = cb_ + lane;
            const int row = c >> 2, sub = c & 3;
            GLLDS(Ahi + (bm + row) * (size_t)lda + k0 + sub * 8, &As[(size_t)cb_ * 8]);
            GLLDS(Bhi + (bn + row) * (size_t)ldb + k0 + sub * 8, &Bs[(size_t)cb_ * 8]);
            if constexpr (SPLIT) {
                GLLDS(Alo + (bm + row) * (size_t)lda + k0 + sub * 8, &As[AT + (size_t)cb_ * 8]);
                GLLDS(Blo + (bn + row) * (size_t)ldb + k0 + sub * 8, &Bs[AT + (size_t)cb_ * 8]);
            }
        }
        __syncthreads();

        bf16x8 ah[4], bh[4], al[4], bl[4];
#pragma unroll
        for (int i = 0; i < 4; ++i) {
            const int ao = (wm * 64 + i * 16 + la) * 32 + lk * 8;
            const int bo = (wn * 64 + i * 16 + la) * 32 + lk * 8;
            ah[i] = *(const bf16x8*)&As[ao];
            bh[i] = *(const bf16x8*)&Bs[bo];
            if constexpr (SPLIT) {
                al[i] = *(const bf16x8*)&As[AT + ao];
                bl[i] = *(const bf16x8*)&Bs[AT + bo];
            }
        }
#pragma unroll
        for (int i = 0; i < 4; ++i)
#pragma unroll
            for (int j = 0; j < 4; ++j) {
                acc[i][j] = __builtin_amdgcn_mfma_f32_16x16x32_bf16(ah[i], bh[j], acc[i][j], 0, 0, 0);
                if constexpr (SPLIT) {
                    acc[i][j] = __builtin_amdgcn_mfma_f32_16x16x32_bf16(al[i], bh[j], acc[i][j], 0, 0, 0);
                    acc[i][j] = __builtin_amdgcn_mfma_f32_16x16x32_bf16(ah[i], bl[j], acc[i][j], 0, 0, 0);
                }
            }
        __syncthreads();
    }

    const int colb = (int)bn + wn * 64 + la;
    float bj[4];
#pragma unroll
    for (int j = 0; j < 4; ++j) bj[j] = biasp[colb + j * 16];
    if constexpr (KSPLIT) {
        if (kc != 0) {
#pragma unroll
            for (int j = 0; j < 4; ++j) bj[j] = 0.f;
        }
    }
#pragma unroll
    for (int i = 0; i < 4; ++i) {
        const int rb = (int)bm + wm * 64 + i * 16 + lk * 4;
#pragma unroll
        for (int j = 0; j < 4; ++j) {
            const int col = colb + j * 16;
#pragma unroll
            for (int r = 0; r < 4; ++r) {
                float v = acc[i][j][r] + bj[j];
                const size_t idx = (size_t)(rb + r) * N + col;
                if constexpr (EPI == 0) Cf[idx] = v;
                if constexpr (EPI == 1) Cf[idx] = tanhf(v);
                if constexpr (EPI == 2) Cb[idx] = bf16rne(tanhf(v));
                if constexpr (EPI == 3) {
                    float tv = tanhf(v);
                    uint16_t h = bf16rne(tv);
                    Chi[idx] = h;
                    Clo[idx] = bf16rne(tv - b2f(h));
                }
            }
        }
    }
}

// ------- wconv2: W f32 [K+1][N] -> T bf16 [N][K], 64x64 tile, coalesced ----
// Phase 1: coalesced 256B-row loads into padded LDS [64][65] (column reads
// then 2-way = free). Phase 2: each thread converts one n-row x 16 k and
// writes 32B contiguous along K.
template <bool SPLIT>
__global__ __launch_bounds__(256) void wconv2(const float* __restrict__ W,
                                              uint16_t* __restrict__ Thi,
                                              uint16_t* __restrict__ Tlo,
                                              int K, int N) {
    __shared__ float t[64][65];
    const int k0 = blockIdx.x * 64, n0 = blockIdx.y * 64;
    const int tid = threadIdx.x;
    {
        const int nq = (tid & 15) * 4;
        const int kl = tid >> 4;
#pragma unroll
        for (int p = 0; p < 4; ++p) {
            const int k = kl + p * 16;
            float4 v = *(const float4*)(W + (size_t)(k0 + k) * N + n0 + nq);
            t[k][nq + 0] = v.x;
            t[k][nq + 1] = v.y;
            t[k][nq + 2] = v.z;
            t[k][nq + 3] = v.w;
        }
    }
    __syncthreads();
    {
        const int nr = tid >> 2;             // 0..63
        const int kc = (tid & 3) * 16;       // 0,16,32,48
        uint16_t hi16[16], lo16[16];
#pragma unroll
        for (int i = 0; i < 16; ++i) {
            float f = t[kc + i][nr];
            uint16_t h = bf16rne(f);
            hi16[i] = h;
            if (SPLIT) lo16[i] = bf16rne(f - b2f(h));
        }
        uint16_t* dst = Thi + (size_t)(n0 + nr) * K + k0 + kc;
        *(uint4*)(dst) = *(const uint4*)(hi16);
        *(uint4*)(dst + 8) = *(const uint4*)(hi16 + 8);
        if (SPLIT) {
            uint16_t* dl = Tlo + (size_t)(n0 + nr) * K + k0 + kc;
            *(uint4*)(dl) = *(const uint4*)(lo16);
            *(uint4*)(dl + 8) = *(const uint4*)(lo16 + 8);
        }
    }
}

// ---------------- x -> hi/lo bf16 split ----------------
__global__ __launch_bounds__(256) void split_x(const float* __restrict__ x,
                                               uint16_t* __restrict__ hi,
                                               uint16_t* __restrict__ lo,
                                               size_t n4) {
    for (size_t i = (size_t)blockIdx.x * 256 + threadIdx.x; i < n4;
         i += (size_t)gridDim.x * 256) {
        float4 v = ((const float4*)x)[i];
        ushort4 h, l;
        h.x = bf16rne(v.x); l.x = bf16rne(v.x - b2f(h.x));
        h.y = bf16rne(v.y); l.y = bf16rne(v.y - b2f(h.y));
        h.z = bf16rne(v.z); l.z = bf16rne(v.z - b2f(h.z));
        h.w = bf16rne(v.w); l.w = bf16rne(v.w - b2f(h.w));
        ((ushort4*)hi)[i] = h;
        ((ushort4*)lo)[i] = l;
    }
}

// ---------------- VQ (NPART>0: h = partials, sum+tanh fused) -------------
template <bool YB16, int NPART>
__global__ __launch_bounds__(256) void vq_kernel(
    const float* __restrict__ h, size_t pstride,
    const float* __restrict__ cb,
    const uint32_t* __restrict__ nlp,
    float* __restrict__ yf, uint16_t* __restrict__ yb,
    uint32_t ka0, uint32_t ka1, uint32_t kb0, uint32_t kb1,
    uint32_t kc0, uint32_t kc1, uint32_t kd0, uint32_t kd1) {
    __shared__ float xs[DCODE];
    __shared__ float sred[NCODE];
    __shared__ int sidx[NCODE];

    const int b = blockIdx.x;
    const int chunk = blockIdx.y;
    const int c = threadIdx.x;

    if (c < DCODE) {
        const size_t idx = (size_t)b * NCODE + chunk * DCODE + c;
        if constexpr (NPART > 0) {
            float z = h[idx];
#pragma unroll
            for (int p = 1; p < NPART; ++p) z += h[(size_t)p * pstride + idx];
            xs[c] = tanhf(z);
        } else {
            xs[c] = h[idx];
        }
    }
    __syncthreads();

    float dot = 0.f, x2 = 0.f, c2 = 0.f;
    const float* crow = cb + c * DCODE;
#pragma unroll 8
    for (int i = 0; i < DCODE; ++i) {
        float xv = xs[i], cv = crow[i];
        dot = fmaf(xv, cv, dot);
        x2 = fmaf(xv, xv, x2);
        c2 = fmaf(cv, cv, c2);
    }
    float d = sqrtf(fmaxf(x2 - 2.f * dot + c2, 0.f));
    float logit = -d * 0.125f;

    sred[c] = logit;
    __syncthreads();
    for (int s = 128; s > 0; s >>= 1) {
        if (c < s) sred[c] = fmaxf(sred[c], sred[c + s]);
        __syncthreads();
    }
    float mx = sred[0];
    __syncthreads();
    float e = expf(logit - mx);
    sred[c] = e;
    __syncthreads();
    for (int s = 128; s > 0; s >>= 1) {
        if (c < s) sred[c] = sred[c] + sred[c + s];
        __syncthreads();
    }
    float ssum = sred[0];
    __syncthreads();
    float r = e / ssum;

    int vi = (int)nlp[0];
    float noise_level = (vi >= -1000000 && vi <= 1000000)
                            ? (float)vi
                            : __uint_as_float(nlp[0]);

    uint32_t lin = (uint32_t)b * 256u + (uint32_t)c;
    uint32_t k0 = chunk == 0 ? ka0 : chunk == 1 ? kb0 : chunk == 2 ? kc0 : kd0;
    uint32_t k1 = chunk == 0 ? ka1 : chunk == 1 ? kb1 : chunk == 2 ? kc1 : kd1;
    uint32_t x0 = 0u, x1 = lin;
    tf2x32(k0, k1, x0, x1);
    uint32_t bits = x0 ^ x1;
    float noise = __uint_as_float((bits >> 9) | 0x3f800000u) - 1.0f;

    float score = r - noise_level * noise;

    sred[c] = score;
    sidx[c] = c;
    __syncthreads();
    for (int s = 128; s > 0; s >>= 1) {
        if (c < s) {
            float ov = sred[c + s];
            int oi = sidx[c + s];
            if (ov > sred[c] || (ov == sred[c] && oi < sidx[c])) {
                sred[c] = ov;
                sidx[c] = oi;
            }
        }
        __syncthreads();
    }
    int best = sidx[0];

    if (c < DCODE) {
        float v = cb[(size_t)best * DCODE + c];
        if constexpr (YB16)
            yb[(size_t)b * NCODE + chunk * DCODE + c] = bf16rne(v);
        else
            yf[(size_t)b * NCODE + chunk * DCODE + c] = v;
    }
}

// ---------------- fallback f32 GEMM (verified Round-4 path) ----------------
template <int BM, int BN, bool TANH>
__global__ __launch_bounds__(256) void gemm_f32(const float* __restrict__ A,
                                                const float* __restrict__ W,
                                                float* __restrict__ C,
                                                int M, int N, int K) {
    constexpr int BK = 16;
    constexpr int TM = BM / 16, TN = BN / 16;
    constexpr int GM = TM / 4, GN = TN / 4;
    constexpr int PA = BM + 4, PB = BN + 4;
    __shared__ float As[BK][PA];
    __shared__ float Bs[BK][PB];

    const int tid = threadIdx.x;
    const int tx = tid & 15, ty = tid >> 4;
    const size_t bm = (size_t)blockIdx.y * BM;
    const size_t bn = (size_t)blockIdx.x * BN;

    float acc[TM][TN];
#pragma unroll
    for (int i = 0; i < TM; ++i)
#pragma unroll
        for (int j = 0; j < TN; ++j) acc[i][j] = 0.f;

    for (int k0 = 0; k0 < K; k0 += BK) {
#pragma unroll
        for (int i = 0; i < BM * BK / 4 / 256; ++i) {
            int f4 = tid + i * 256;
            int row = f4 >> 2;
            int c4 = f4 & 3;
            float4 v = *reinterpret_cast<const float4*>(A + (bm + row) * K + k0 + c4 * 4);
            As[c4 * 4 + 0][row] = v.x;
            As[c4 * 4 + 1][row] = v.y;
            As[c4 * 4 + 2][row] = v.z;
            As[c4 * 4 + 3][row] = v.w;
        }
#pragma unroll
        for (int i = 0; i < BK * BN / 4 / 256; ++i) {
            int f4 = tid + i * 256;
            int row = f4 / (BN / 4);
            int c4 = f4 % (BN / 4);
            *reinterpret_cast<float4*>(&Bs[row][c4 * 4]) =
                *reinterpret_cast<const float4*>(W + (size_t)(k0 + row) * N + bn + c4 * 4);
        }
        __syncthreads();
#pragma unroll
        for (int k = 0; k < BK; ++k) {
            float4 af[GM], bf[GN];
#pragma unroll
            for (int g = 0; g < GM; ++g)
                af[g] = *reinterpret_cast<const float4*>(&As[k][g * 64 + ty * 4]);
#pragma unroll
            for (int g = 0; g < GN; ++g)
                bf[g] = *reinterpret_cast<const float4*>(&Bs[k][g * 64 + tx * 4]);
#pragma unroll
            for (int gm = 0; gm < GM; ++gm) {
                const float* ap = &af[gm].x;
#pragma unroll
                for (int r = 0; r < 4; ++r) {
#pragma unroll
                    for (int gn = 0; gn < GN; ++gn) {
                        const float* bp = &bf[gn].x;
#pragma unroll
                        for (int c = 0; c < 4; ++c)
                            acc[gm * 4 + r][gn * 4 + c] =
                                fmaf(ap[r], bp[c], acc[gm * 4 + r][gn * 4 + c]);
                    }
                }
            }
        }
        __syncthreads();
    }

#pragma unroll
    for (int gm = 0; gm < GM; ++gm) {
#pragma unroll
        for (int r = 0; r < 4; ++r) {
            size_t row = bm + gm * 64 + ty * 4 + r;
#pragma unroll
            for (int gn = 0; gn < GN; ++gn) {
                size_t col = bn + gn * 64 + tx * 4;
                float4 bias = *reinterpret_cast<const float4*>(W + (size_t)K * N + col);
                float4 o;
                o.x = acc[gm * 4 + r][gn * 4 + 0] + bias.x;
                o.y = acc[gm * 4 + r][gn * 4 + 1] + bias.y;
                o.z = acc[gm * 4 + r][gn * 4 + 2] + bias.z;
                o.w = acc[gm * 4 + r][gn * 4 + 3] + bias.w;
                if (TANH) {
                    o.x = tanhf(o.x); o.y = tanhf(o.y);
                    o.z = tanhf(o.z); o.w = tanhf(o.w);
                }
                *reinterpret_cast<float4*>(C + row * N + col) = o;
            }
        }
    }
}

// ---------------- launch ----------------
extern "C" void kernel_launch(void* const* d_in, const int* in_sizes, int n_in,
                              void* d_out, int out_size, void* d_ws, size_t ws_size,
                              hipStream_t stream) {
    const float* x   = (const float*)d_in[0];
    const float* w1e = (const float*)d_in[1];
    const float* w2e = (const float*)d_in[2];
    const float* w1d = (const float*)d_in[3];
    const float* w2d = (const float*)d_in[4];
    const float* cb1 = (const float*)d_in[5];
    const uint32_t* nl = (const uint32_t*)d_in[9];
    float* out = (float*)d_out;

    const int M = in_sizes[0] / IMG_DIM;  // 4096

    uint32_t ks[4][2];
    for (int j = 1; j <= 4; ++j) {
        uint32_t a = 0u, bb = (uint32_t)j;
        tf2x32(0u, 12345u, a, bb);
        ks[j - 1][0] = a;
        ks[j - 1][1] = bb;
    }

    // ws layout (bytes), with time-aliasing:
    const size_t o_h1hi  = 0;           // 134217728  (later: h2 bf16)
    const size_t o_h1lo  = 134217728;   // 134217728
    const size_t o_w1ehi = 268435456;   // 100663296  (later: Wt2d)
    const size_t o_w1elo = 369098752;   // 100663296  (later: Wt1d)
    const size_t o_w2ehi = 469762048;   // 8388608
    const size_t o_w2elo = 478150656;   // 8388608
    const size_t o_h     = 486539264;   // 4194304 (unused in main path)
    const size_t o_y     = 490733568;   // 2097152
    const size_t o_xhi   = 492830720;   // 25165824 (aliased: E2 partials, 16.8MB)
    const size_t o_xlo   = 517996544;   // 25165824
    const size_t NEED    = 543162368;

    uint8_t* ws = (uint8_t*)d_ws;

    if (ws_size >= NEED) {
        uint16_t* h1hi  = (uint16_t*)(ws + o_h1hi);
        uint16_t* h1lo  = (uint16_t*)(ws + o_h1lo);
        uint16_t* w1ehi = (uint16_t*)(ws + o_w1ehi);
        uint16_t* w1elo = (uint16_t*)(ws + o_w1elo);
        uint16_t* w2ehi = (uint16_t*)(ws + o_w2ehi);
        uint16_t* w2elo = (uint16_t*)(ws + o_w2elo);
        uint16_t* ybuf  = (uint16_t*)(ws + o_y);
        uint16_t* xhi   = (uint16_t*)(ws + o_xhi);
        uint16_t* xlo   = (uint16_t*)(ws + o_xlo);
        uint16_t* wt2d  = (uint16_t*)(ws + o_w1ehi);  // alias after E1
        uint16_t* wt1d  = (uint16_t*)(ws + o_w1elo);  // alias after E1
        uint16_t* h2    = (uint16_t*)(ws + o_h1hi);   // alias after E2
        float*    e2p   = (float*)(ws + o_xhi);       // alias after E1

        const size_t aLo = (o_xlo - o_xhi) / 2;       // 12582912
        const size_t bLo = (o_w1elo - o_w1ehi) / 2;   // 50331648

        // prep
        split_x<<<2048, 256, 0, stream>>>(x, xhi, xlo, (size_t)M * IMG_DIM / 4);
        wconv2<true><<<dim3(IMG_DIM / 64, HID / 64), 256, 0, stream>>>(w1e, w1ehi, w1elo, IMG_DIM, HID);
        wconv2<true><<<dim3(HID / 64, NCODE / 64), 256, 0, stream>>>(w2e, w2ehi, w2elo, HID, NCODE);
        // E1 (interleaved-swizzled): h1 = tanh(x @ w1e + b) -> bf16 hi/lo
        gemm_ilv<<<dim3(HID / 128, M / 128), 256, 0, stream>>>(
            xhi, aLo, w1ehi, bLo, w1e + (size_t)IMG_DIM * HID,
            h1hi, h1lo, M, HID, IMG_DIM, IMG_DIM, IMG_DIM);
        // decoder weight conversions (into regions freed by E1)
        wconv2<false><<<dim3(HID / 64, IMG_DIM / 64), 256, 0, stream>>>(w2d, wt2d, nullptr, HID, IMG_DIM);
        wconv2<false><<<dim3(NCODE / 64, HID / 64), 256, 0, stream>>>(w1d, wt1d, nullptr, NCODE, HID);
        // E2 split-K x4 (one dispatch, 256 blocks): partials into e2p
        gemm_mfma<0, true, true><<<dim3(NCODE / 128, M / 128, 4), 256, 0, stream>>>(
            h1hi, h1lo, w2ehi, w2elo, w2e + (size_t)HID * NCODE,
            e2p, nullptr, nullptr, nullptr, M, NCODE, HID / 4, HID, HID);
        // VQ (fused partial-sum + tanh) -> y bf16
        vq_kernel<true, 4><<<dim3(M, 4), 256, 0, stream>>>(
            e2p, (size_t)M * NCODE, cb1, nl, nullptr, ybuf,
            ks[0][0], ks[0][1], ks[1][0], ks[1][1],
            ks[2][0], ks[2][1], ks[3][0], ks[3][1]);
        // D1: h2 = tanh(y @ w1d + b) -> bf16
        gemm_mfma<2, false, false><<<dim3(HID / 128, M / 128), 256, 0, stream>>>(
            ybuf, nullptr, wt1d, nullptr, w1d + (size_t)NCODE * HID,
            nullptr, h2, nullptr, nullptr, M, HID, NCODE, NCODE, NCODE);
        // D2: out = h2 @ w2d + b -> f32
        gemm_mfma<0, false, false><<<dim3(IMG_DIM / 128, M / 128), 256, 0, stream>>>(
            h2, nullptr, wt2d, nullptr, w2d + (size_t)HID * IMG_DIM,
            out, nullptr, nullptr, nullptr, M, IMG_DIM, HID, HID, HID);
    } else {
        // fallback: verified f32 path
        float* h1 = (float*)d_ws;
        float* h  = h1 + (size_t)M * HID;
        float* yb = h + (size_t)M * NCODE;
        {
            dim3 g(HID / 128, M / 128);
            gemm_f32<128, 128, true><<<g, 256, 0, stream>>>(x, w1e, h1, M, HID, IMG_DIM);
        }
        {
            dim3 g(NCODE / 64, M / 64);
            gemm_f32<64, 64, true><<<g, 256, 0, stream>>>(h1, w2e, h, M, NCODE, HID);
        }
        vq_kernel<false, 0><<<dim3(M, 4), 256, 0, stream>>>(
            h, 0, cb1, nl, yb, nullptr,
            ks[0][0], ks[0][1], ks[1][0], ks[1][1],
            ks[2][0], ks[2][1], ks[3][0], ks[3][1]);
        {
            dim3 g(HID / 128, M / 128);
            gemm_f32<128, 128, true><<<g, 256, 0, stream>>>(yb, w1d, h1, M, HID, NCODE);
        }
        {
            dim3 g(IMG_DIM / 128, M / 128);
            gemm_f32<128, 128, false><<<g, 256, 0, stream>>>(h1, w2d, out, M, IMG_DIM, HID);
        }
    }
}